// Round 7
// baseline (203.585 us; speedup 1.0000x reference)
//
#include <hip/hip_runtime.h>
#include <stdint.h>

// Self-attention: x[4,2048,768] fp32, W_q/W_k/W_v [768,768] fp32 -> out[4,2048,768] fp32.
//
// v12: algebraic K-elimination + launch merging (cores held fixed from v11).
//  - S = x(WqWk^T)x^T: gemm_m precomputes Mt = Wk.Wq^T (0.9 GFLOP) packed as a
//    B-operand; proj computes Q' = x.Mt (and V^T) only -> grid 576->384; S-GEMM's
//    B operand is xbp (already packed). K-projection + K buffer deleted.
//  - pack_all: ONE kernel = x-pack (3072 blk) + Wv-transpose-pack (576) +
//    Wq/Wk natural-pack (576). l-zeroing folded into gemm_m. memset deleted.
//    7 launches -> 5.
//  - s_exp256 (256^2 quad-buffered core, atomic row-sum), PV (128^2 core),
//    XCD swizzles, g-ladder: unchanged from v11.
//
// Packed layout: operand = [row-block r/128][it = k/64][16 KB chunk]; chunk =
// [p = k-octet 0..8][r 0..128][8 u16]. A 32-k piece = half-chunk = 4096 u16.

typedef unsigned short u16;
typedef unsigned int u32;

typedef __attribute__((ext_vector_type(4))) float f32x4;
typedef __attribute__((ext_vector_type(8))) __bf16 bf16x8;
typedef __attribute__((ext_vector_type(8))) short s16x8;
typedef __attribute__((ext_vector_type(8))) unsigned short us16x8;

template <class T> T&& declv();
template <typename T, typename V = void>
struct mfma_ok { static constexpr bool value = false; };
template <typename T>
struct mfma_ok<T, decltype((void)__builtin_amdgcn_mfma_f32_16x16x32_bf16(
                     declv<T>(), declv<T>(), declv<f32x4>(), 0, 0, 0))> {
  static constexpr bool value = true;
};
template <bool BF, bool S16> struct pick_frag { typedef us16x8 type; };
template <bool S16> struct pick_frag<true, S16> { typedef bf16x8 type; };
template <> struct pick_frag<false, true> { typedef s16x8 type; };
typedef typename pick_frag<mfma_ok<bf16x8>::value, mfma_ok<s16x8>::value>::type frag_t;

__device__ inline f32x4 mfma16x16x32(frag_t a, frag_t b, f32x4 c) {
  return __builtin_amdgcn_mfma_f32_16x16x32_bf16(a, b, c, 0, 0, 0);
}

#define AS3(p) ((__attribute__((address_space(3))) void*)(p))
#define AS1c(p) ((__attribute__((address_space(1))) void*)(const void*)(p))

__device__ inline u16 f2bf(float f) {
  union { float f; u32 u; } v; v.f = f;
  u32 r = v.u + 0x7fffu + ((v.u >> 16) & 1u);  // RNE
  return (u16)(r >> 16);
}

#define GR 8192        // u16 per it-chunk (16 KB)
#define BOFF4 8192     // u16 offset of B half of LDS (128^2 loop)

// =====================================================================
// 128x128 / 4-wave loop — gemm_pv and gemm_m.
// =====================================================================
__device__ inline void gemm_loop4(u16* smem, const u16* __restrict__ Ap,
                                  const u16* __restrict__ Bp, int nit,
                                  f32x4 acc[4][4])
{
  const int tid  = threadIdx.x;
  const int lane = tid & 63;
  const int wave = tid >> 6;
  const int quad = lane >> 4;
  const int l16  = lane & 15;
  const int wm   = (wave & 1) * 64;
  const int wn   = (wave >> 1) * 64;
  const int so   = wave * 2048;
  const int lo   = lane << 3;

#pragma unroll
  for (int i = 0; i < 4; i++)
#pragma unroll
    for (int j = 0; j < 4; j++) acc[i][j] = f32x4{0.f, 0.f, 0.f, 0.f};

  for (int it = 0; it < nit; ++it) {
    const long o = (long)it * GR;
    __syncthreads();
#pragma unroll
    for (int j = 0; j < 4; j++) {
      __builtin_amdgcn_global_load_lds(AS1c(Ap + o + so + j * 512 + lo),
                                       AS3(smem + so + j * 512), 16, 0, 0);
      __builtin_amdgcn_global_load_lds(AS1c(Bp + o + so + j * 512 + lo),
                                       AS3(smem + BOFF4 + so + j * 512), 16, 0, 0);
    }
    __syncthreads();

#pragma unroll
    for (int s = 0; s < 2; s++) {
      frag_t af[4], bf_[4];
#pragma unroll
      for (int mt = 0; mt < 4; mt++)
        af[mt] = *(const frag_t*)(&smem[(s * 4 + quad) * 1024 + (wm + mt * 16 + l16) * 8]);
#pragma unroll
      for (int nt = 0; nt < 4; nt++)
        bf_[nt] = *(const frag_t*)(&smem[BOFF4 + (s * 4 + quad) * 1024 + (wn + nt * 16 + l16) * 8]);
#pragma unroll
      for (int mt = 0; mt < 4; mt++)
#pragma unroll
        for (int nt = 0; nt < 4; nt++)
          acc[mt][nt] = mfma16x16x32(af[mt], bf_[nt], acc[mt][nt]);
    }
  }
}

// 128x128 tile -> 2 contiguous packed it-chunks (16384 u16) at dst.
__device__ __forceinline__ void epilogue_packed(u16* smem, u16* __restrict__ dst,
                                                f32x4 acc[4][4])
{
  const int tid  = threadIdx.x;
  const int lane = tid & 63;
  const int wave = tid >> 6;
  const int quad = lane >> 4;
  const int l16  = lane & 15;
  const int wm   = (wave & 1) * 64;
  const int wn   = (wave >> 1) * 64;

  __syncthreads();
#pragma unroll
  for (int mt = 0; mt < 4; mt++)
#pragma unroll
    for (int nt = 0; nt < 4; nt++) {
      const int nl = wn + nt * 16 + l16;
      const int base = ((nl >> 3) & 7) * 1024 + (nl & 7) + (nl >> 6) * 8192;
#pragma unroll
      for (int i = 0; i < 4; i++) {
        const int r = wm + mt * 16 + quad * 4 + i;
        smem[base + r * 8] = f2bf(acc[mt][nt][i]);
      }
    }
  __syncthreads();
#pragma unroll
  for (int k = 0; k < 8; k++) {
    const int idx = tid * 8 + k * 2048;
    *(uint4*)(dst + idx) = *(const uint4*)(smem + idx);
  }
}

// =====================================================================
// 256x128 / 8-wave / BK=32 / triple-buffered core (72 KiB LDS) — proj.
// =====================================================================
__device__ __forceinline__ void gemm128c_loop(u16* smem,
    const u16* __restrict__ A0, const u16* __restrict__ A1,
    const u16* __restrict__ B0, int nt32, f32x4 acc[4][4])
{
  const int tid   = threadIdx.x;
  const int lane  = tid & 63;
  const int wave  = tid >> 6;      // 0..7
  const int quad  = lane >> 4;
  const int l16   = lane & 15;
  const int waveM = wave >> 1;     // 0..3 (64-row strip)
  const int waveN = wave & 1;      // 0..1 (64-col strip)
  const int wch   = wave * 512;    // wave chunk within a 4096-u16 piece
  const int go    = tid * 8;       // per-lane global offset (u16)

#pragma unroll
  for (int i = 0; i < 4; i++)
#pragma unroll
    for (int j = 0; j < 4; j++) acc[i][j] = f32x4{0.f, 0.f, 0.f, 0.f};

#define STG3(T, BUF) do {                                                      \
    const long _p = (long)(T) * 4096;                                          \
    const int _b = (BUF) * 12288 + wch;                                        \
    __builtin_amdgcn_global_load_lds(AS1c(A0 + _p + go), AS3(smem + _b),       \
                                     16, 0, 0);                                \
    __builtin_amdgcn_global_load_lds(AS1c(A1 + _p + go), AS3(smem + _b + 4096),\
                                     16, 0, 0);                                \
    __builtin_amdgcn_global_load_lds(AS1c(B0 + _p + go), AS3(smem + _b + 8192),\
                                     16, 0, 0);                                \
  } while (0)

  STG3(0, 0);
  STG3(1, 1);
  asm volatile("s_waitcnt vmcnt(3)" ::: "memory");
  __builtin_amdgcn_s_barrier();

  const int ablk = (waveM >> 1) * 4096;
  const int arow = ((waveM & 1) * 64 + l16) * 8;
  const int brow = (waveN * 64 + l16) * 8;

  int bc = 0;  // t % 3
  for (int t = 0; t < nt32; ++t) {
    const int bb = bc * 12288;
    frag_t af[4], bfr[4];
#pragma unroll
    for (int mt = 0; mt < 4; mt++)
      af[mt] = *(const frag_t*)(smem + bb + ablk + quad * 1024 + arow + mt * 128);
#pragma unroll
    for (int nt = 0; nt < 4; nt++)
      bfr[nt] = *(const frag_t*)(smem + bb + 8192 + quad * 1024 + brow + nt * 128);

    if (t + 2 < nt32) {
      const int sc = bc == 0 ? 2 : bc - 1;  // (t+2) % 3
      STG3(t + 2, sc);
    }
    __builtin_amdgcn_s_barrier();
    asm volatile("s_waitcnt lgkmcnt(0)" ::: "memory");
    __builtin_amdgcn_sched_barrier(0);
    __builtin_amdgcn_s_setprio(1);
#pragma unroll
    for (int mt = 0; mt < 4; mt++)
#pragma unroll
      for (int nt = 0; nt < 4; nt++)
        acc[mt][nt] = mfma16x16x32(af[mt], bfr[nt], acc[mt][nt]);
    __builtin_amdgcn_s_setprio(0);

    if (t + 3 <= nt32)      { asm volatile("s_waitcnt vmcnt(3)" ::: "memory"); }
    else if (t + 2 <= nt32) { asm volatile("s_waitcnt vmcnt(0)" ::: "memory"); }
    __builtin_amdgcn_s_barrier();
    bc = bc == 2 ? 0 : bc + 1;
  }
#undef STG3
}

// =====================================================================
// 256x256 / 8-wave / BK=32 / quad-buffered core (128 KiB LDS) — s_exp.
// =====================================================================
__device__ __forceinline__ void gemm256_loop(u16* smem,
    const u16* __restrict__ A0, const u16* __restrict__ A1,
    const u16* __restrict__ B0, const u16* __restrict__ B1,
    int nt32, f32x4 acc[8][4])
{
  const int tid   = threadIdx.x;
  const int lane  = tid & 63;
  const int wave  = tid >> 6;      // 0..7
  const int quad  = lane >> 4;
  const int l16   = lane & 15;
  const int waveM = wave >> 2;     // 0..1
  const int waveN = wave & 3;      // 0..3
  const int wch   = wave * 512;
  const int lo    = lane * 8;

#pragma unroll
  for (int i = 0; i < 8; i++)
#pragma unroll
    for (int j = 0; j < 4; j++) acc[i][j] = f32x4{0.f, 0.f, 0.f, 0.f};

#define STAGE2(PA, PB, T, PBASE) do {                                          \
    const long _o = ((long)((T) >> 1) << 13) + (long)(((T) & 1) << 12);        \
    const int _db = (((T) & 3) << 14) + ((PBASE) << 12) + wch;                 \
    __builtin_amdgcn_global_load_lds(AS1c((PA) + _o + wch + lo),               \
                                     AS3(smem + _db), 16, 0, 0);               \
    __builtin_amdgcn_global_load_lds(AS1c((PB) + _o + wch + lo),               \
                                     AS3(smem + _db + 4096), 16, 0, 0);        \
  } while (0)

  STAGE2(A0, A1, 0, 0); STAGE2(B0, B1, 0, 2);
  STAGE2(A0, A1, 1, 0); STAGE2(B0, B1, 1, 2);
  STAGE2(A0, A1, 2, 0); STAGE2(B0, B1, 2, 2);
  asm volatile("s_waitcnt vmcnt(8)" ::: "memory");
  __builtin_amdgcn_s_barrier();

  for (int t = 0; t < nt32; ++t) {
    const int bb = (t & 3) << 14;
    const int aB = bb + (waveM << 12) + quad * 1024 + l16 * 8;
    const int bB = bb + 8192 + ((waveN >> 1) << 12) + quad * 1024
                 + ((waveN & 1) * 64 + l16) * 8;
    frag_t af[4], bfr[4];

    // ---- phase 0 (row-half 0) ----
#pragma unroll
    for (int nt = 0; nt < 4; nt++) bfr[nt] = *(const frag_t*)(smem + bB + nt * 128);
#pragma unroll
    for (int mt = 0; mt < 4; mt++) af[mt] = *(const frag_t*)(smem + aB + mt * 128);
    if (t + 3 < nt32) STAGE2(A0, A1, t + 3, 0);
    __builtin_amdgcn_s_barrier();
    asm volatile("s_waitcnt lgkmcnt(0)" ::: "memory");
    __builtin_amdgcn_sched_barrier(0);
    __builtin_amdgcn_s_setprio(1);
#pragma unroll
    for (int mt = 0; mt < 4; mt++)
#pragma unroll
      for (int nt = 0; nt < 4; nt++)
        acc[mt][nt] = mfma16x16x32(af[mt], bfr[nt], acc[mt][nt]);
    __builtin_amdgcn_s_setprio(0);
    __builtin_amdgcn_s_barrier();

    // ---- phase 1 (row-half 1) ----
#pragma unroll
    for (int mt = 0; mt < 4; mt++) af[mt] = *(const frag_t*)(smem + aB + 512 + mt * 128);
    if (t + 3 < nt32) STAGE2(B0, B1, t + 3, 2);
    __builtin_amdgcn_s_barrier();
    asm volatile("s_waitcnt lgkmcnt(0)" ::: "memory");
    __builtin_amdgcn_sched_barrier(0);
    __builtin_amdgcn_s_setprio(1);
#pragma unroll
    for (int mt = 0; mt < 4; mt++)
#pragma unroll
      for (int nt = 0; nt < 4; nt++)
        acc[4 + mt][nt] = mfma16x16x32(af[mt], bfr[nt], acc[4 + mt][nt]);
    __builtin_amdgcn_s_setprio(0);

    if (t + 4 <= nt32)      { asm volatile("s_waitcnt vmcnt(8)" ::: "memory"); }
    else if (t + 3 <= nt32) { asm volatile("s_waitcnt vmcnt(4)" ::: "memory"); }
    else if (t + 2 <= nt32) { asm volatile("s_waitcnt vmcnt(0)" ::: "memory"); }
    __builtin_amdgcn_s_barrier();
  }
#undef STAGE2
}

// Exp + packed + atomic row-sum epilogue for the 256^2 S-tile.
__device__ __forceinline__ void epi_exp256(u16* smem, u16* __restrict__ dst0,
                                           u16* __restrict__ dst1,
                                           float* __restrict__ lG,
                                           f32x4 acc[8][4], float qscale)
{
  const int tid   = threadIdx.x;
  const int lane  = tid & 63;
  const int wave  = tid >> 6;
  const int quad  = lane >> 4;
  const int l16   = lane & 15;
  const int waveM = wave >> 2;
  const int waveN = wave & 3;
  float* lrow = (float*)(smem + 65536);  // [256][4] floats (4 KB)

  __syncthreads();
  float s[8][4];
#pragma unroll
  for (int m8 = 0; m8 < 8; m8++)
#pragma unroll
    for (int i = 0; i < 4; i++) s[m8][i] = 0.f;

#pragma unroll
  for (int m8 = 0; m8 < 8; m8++)
#pragma unroll
    for (int nt = 0; nt < 4; nt++) {
      const int base = waveM * 32768 + waveN * 8192 + (nt * 2 + (l16 >> 3)) * 1024
                     + (l16 & 7);
#pragma unroll
      for (int i = 0; i < 4; i++) {
        const int r = m8 * 16 + quad * 4 + i;
        float ev = __expf(acc[m8][nt][i] * qscale);
        smem[base + r * 8] = f2bf(ev);
        s[m8][i] += ev;
      }
    }
#pragma unroll
  for (int m8 = 0; m8 < 8; m8++)
#pragma unroll
    for (int i = 0; i < 4; i++) {
      float v = s[m8][i];
      v += __shfl_xor(v, 1, 16);
      v += __shfl_xor(v, 2, 16);
      v += __shfl_xor(v, 4, 16);
      v += __shfl_xor(v, 8, 16);
      if (l16 == 0)
        lrow[(waveM * 128 + m8 * 16 + quad * 4 + i) * 4 + waveN] = v;
    }
  __syncthreads();
#pragma unroll
  for (int k = 0; k < 8; k++) {
    const int idx = k * 4096 + tid * 8;
    *(uint4*)(dst0 + idx) = *(const uint4*)(smem + idx);
    *(uint4*)(dst1 + idx) = *(const uint4*)(smem + 32768 + idx);
  }
  if (tid < 256)
    atomicAdd(&lG[tid],
              lrow[tid * 4] + lrow[tid * 4 + 1] + lrow[tid * 4 + 2] + lrow[tid * 4 + 3]);
}

// Packed bf16 epilogue for a 256x128 tile (proj).
__device__ __forceinline__ void epi_pack_rc(u16* smem, u16* __restrict__ dst0,
                                            u16* __restrict__ dst1, f32x4 acc[4][4])
{
  const int tid   = threadIdx.x;
  const int lane  = tid & 63;
  const int wave  = tid >> 6;
  const int quad  = lane >> 4;
  const int l16   = lane & 15;
  const int waveM = wave >> 1;
  const int waveN = wave & 1;

  __syncthreads();
  const int base = (waveM >> 1) * 16384 + waveN * 8192 + (l16 >> 3) * 1024 + (l16 & 7);
  const int rr0  = (waveM & 1) * 64 + quad * 4;
#pragma unroll
  for (int mt = 0; mt < 4; mt++)
#pragma unroll
    for (int nt = 0; nt < 4; nt++) {
#pragma unroll
      for (int i = 0; i < 4; i++)
        smem[base + nt * 2048 + (rr0 + mt * 16 + i) * 8] = f2bf(acc[mt][nt][i]);
    }
  __syncthreads();
#pragma unroll
  for (int k = 0; k < 4; k++) {
    const int idx = k * 4096 + tid * 8;
    *(uint4*)(dst0 + idx) = *(const uint4*)(smem + idx);
    *(uint4*)(dst1 + idx) = *(const uint4*)(smem + 16384 + idx);
  }
}

// =====================================================================
// pack_all: merged input packers (one launch, 4224 blocks x 256 thr).
//  [0,3072)      : x fp32 -> xbp packed (8 elems/thread)
//  [3072,3648)   : Wv fp32 -> wtp (transposed pack, 32x32 tiles)
//  [3648,4224)   : Wq,Wk fp32 -> wqn,wkn (natural pack, rows x k=u)
// =====================================================================
__global__ __launch_bounds__(256)
void pack_all(const float* __restrict__ x, const float* __restrict__ Wq,
              const float* __restrict__ Wk, const float* __restrict__ Wv,
              u16* __restrict__ xbp, u16* __restrict__ wtp,
              u16* __restrict__ wqn, u16* __restrict__ wkn)
{
  __shared__ u16 tile[32][33];
  const int bid = blockIdx.x;
  const int tid = threadIdx.x;

  if (bid < 3072) {  // ---- x pack ----
    const int tg = bid * 256 + tid;
    const int m = tg / 96;
    const int g = tg - m * 96;
    const float4* px = (const float4*)(x + (long)m * 768 + g * 8);
    float4 a = px[0], b = px[1];
    uint4 u;
    u.x = (u32)f2bf(a.x) | ((u32)f2bf(a.y) << 16);
    u.y = (u32)f2bf(a.z) | ((u32)f2bf(a.w) << 16);
    u.z = (u32)f2bf(b.x) | ((u32)f2bf(b.y) << 16);
    u.w = (u32)f2bf(b.z) | ((u32)f2bf(b.w) << 16);
    const long addr = (long)(m >> 7) * 98304 + (g >> 3) * GR + (g & 7) * 1024 + (m & 127) * 8;
    *(uint4*)(xbp + addr) = u;
  } else if (bid < 3648) {  // ---- Wv transpose pack ----
    const int b1 = bid - 3072;
    const int bx = (b1 % 24) * 32;  // u base
    const int by = (b1 / 24) * 32;  // d base
    const int tx = tid & 31, ty = tid >> 5;
#pragma unroll
    for (int i = 0; i < 32; i += 8)
      tile[ty + i][tx] = f2bf(Wv[(long)(by + ty + i) * 768 + bx + tx]);
    __syncthreads();
    if (tid < 128) {
      const int ul = tid >> 2, dg = tid & 3;
      const int u = bx + ul, d0 = by + dg * 8;
      uint4 o;
      u32 w_[4];
#pragma unroll
      for (int i = 0; i < 4; i++)
        w_[i] = (u32)tile[dg * 8 + 2 * i][ul] | ((u32)tile[dg * 8 + 2 * i + 1][ul] << 16);
      o.x = w_[0]; o.y = w_[1]; o.z = w_[2]; o.w = w_[3];
      const long addr = (long)(u >> 7) * 98304
                      + (d0 >> 6) * GR + ((d0 >> 3) & 7) * 1024 + (u & 127) * 8;
      *(uint4*)(wtp + addr) = o;
    }
  } else {  // ---- Wq / Wk natural pack ----
    const int b2 = bid - 3648;
    const float* W = (b2 < 288) ? Wq : Wk;
    u16* dst = (b2 < 288) ? wqn : wkn;
    const int t = (b2 < 288 ? b2 : b2 - 288) * 256 + tid;
    const int m = t / 96;
    const int g = t - m * 96;
    const float4* pw = (const float4*)(W + (long)m * 768 + g * 8);
    float4 a = pw[0], b = pw[1];
    uint4 u;
    u.x = (u32)f2bf(a.x) | ((u32)f2bf(a.y) << 16);
    u.y = (u32)f2bf(a.z) | ((u32)f2bf(a.w) << 16);
    u.z = (u32)f2bf(b.x) | ((u32)f2bf(b.y) << 16);
    u.w = (u32)f2bf(b.z) | ((u32)f2bf(b.w) << 16);
    const long addr = (long)(m >> 7) * 98304 + (g >> 3) * GR + (g & 7) * 1024 + (m & 127) * 8;
    *(uint4*)(dst + addr) = u;
  }
}

// =====================================================================
// gemm_m: Mt[e,d] = sum_u Wk[e,u]*Wq[d,u]  (Mt = Wk.Wq^T, 768x768), packed
// as the B-operand of the Q'-projection. Blocks 0..35 = 6x6 128^2 tiles;
// blocks 36..43 zero the atomic row-sum buffer l (8 KB floats).
// =====================================================================
__global__ __launch_bounds__(256)
void gemm_m(const u16* __restrict__ wkn, const u16* __restrict__ wqn,
            u16* __restrict__ mt, float* __restrict__ l)
{
  __shared__ alignas(16) u16 smem[16384];
  const int b = blockIdx.x;
  if (b >= 36) {
    const int idx = (b - 36) * 1024 + threadIdx.x * 4;
    *(float4*)(l + idx) = float4{0.f, 0.f, 0.f, 0.f};
    return;
  }
  f32x4 acc[4][4];
  const int bx = b % 6;  // e row-block
  const int by = b / 6;  // d col-block
  gemm_loop4(smem, wkn + (long)bx * 98304, wqn + (long)by * 98304, 12, acc);
  epilogue_packed(smem, mt + (long)bx * 98304 + (long)(2 * by) * GR, acc);
}

// =====================================================================
// Projection: Q' = x.Mt and V^T = (x Wv)^T, 256x128 tiles: grid 384.
//  x < 192 : Q'-proj, bx = x&31 (256-row tile), by = x>>5 (128-col strip 0..5)
//  x >= 192: V^T-proj, i = x-192, bxv = i>>6 (256-u tile 0..2), byv = i&63
// =====================================================================
__global__ __launch_bounds__(512, 2)
void gemm_proj(const u16* __restrict__ xbp, const u16* __restrict__ wtp,
               const u16* __restrict__ mt, u16* __restrict__ Qp,
               u16* __restrict__ Vtp)
{
  __shared__ alignas(16) u16 smem[36864];
  f32x4 acc[4][4];
  const int x = blockIdx.x;
  const u16 *A0, *A1, *B0;
  u16 *d0, *d1;
  if (x < 192) {
    const int bx = x & 31, by = x >> 5;
    A0 = xbp + (long)(2 * bx) * 98304;  A1 = A0 + 98304;
    B0 = mt + (long)by * 98304;
    d0 = Qp + (long)(2 * bx) * 98304 + (long)(2 * by) * GR;
    d1 = d0 + 98304;
  } else {
    const int i = x - 192;
    const int bxv = i >> 6, byv = i & 63;
    A0 = wtp + (long)(2 * bxv) * 98304;  A1 = A0 + 98304;
    B0 = xbp + (long)byv * 98304;
    d0 = Vtp + (long)(2 * bxv) * 1048576 + (long)(2 * byv) * GR;
    d1 = d0 + 1048576;
  }
  gemm128c_loop(smem, A0, A1, B0, 24, acc);
  epi_pack_rc(smem, d0, d1, acc);
}

// =====================================================================
// S-GEMM + fused exp/atomic-row-sum, 256^2 tiles: grid (8,8,gb).
// B operand = packed x (xb). Bijective XCD chunk swizzle.
// =====================================================================
__global__ __launch_bounds__(512, 2)
void gemm_s_exp256(const u16* __restrict__ Qp, const u16* __restrict__ xb,
                   u16* __restrict__ Pp, float* __restrict__ l, float qscale)
{
  __shared__ alignas(16) u16 smem[67584];  // 128 KB image + 4 KB lrow
  f32x4 acc[8][4];
  const int nb  = (int)gridDim.z << 6;           // 64 * gb (divisible by 8)
  const int u   = (int)blockIdx.x + ((int)blockIdx.y << 3) + ((int)blockIdx.z << 6);
  const int cpx = nb >> 3;
  const int wg  = (u & 7) * cpx + (u >> 3);      // bijective chunked swizzle
  const int bx = wg & 7, by = (wg >> 3) & 7, z = wg >> 6;

  const u16* A0 = Qp + (long)(z * 16 + 2 * bx) * 98304;
  const u16* B0 = xb + (long)(z * 16 + 2 * by) * 98304;
  gemm256_loop(smem, A0, A0 + 98304, B0, B0 + 98304, 24, acc);
  u16* d0 = Pp + (long)z * 4194304 + (long)(2 * bx) * 262144 + (long)(4 * by) * GR;
  epi_exp256(smem, d0, d0 + 262144, l + z * 2048 + bx * 256, acc, qscale);
}

// =====================================================================
// One-shot PV (K=2048, NIT=32), grid (16,6,gb); reads 1/l directly.
// =====================================================================
__global__ __launch_bounds__(256)
void gemm_pv(const u16* __restrict__ Pp, const u16* __restrict__ Vtp_off,
             const float* __restrict__ l, float* __restrict__ out)
{
  __shared__ alignas(16) u16 smem[16384];
  f32x4 acc[4][4];
  const long SU = 2048L * 768;
  const int nb  = 96 * (int)gridDim.z;           // 96*gb (divisible by 8)
  const int u   = (int)blockIdx.x + ((int)blockIdx.y << 4) + (int)blockIdx.z * 96;
  const int cpx = nb >> 3;
  const int wg  = (u & 7) * cpx + (u >> 3);
  const int bx = wg & 15, by = (wg >> 4) % 6, z = wg / 96;

  gemm_loop4(smem,
             Pp + (long)z * 4194304 + (long)bx * 262144,
             Vtp_off + (long)by * 1048576 + (long)(z * 32) * GR,
             32, acc);

  __syncthreads();
  float* lsl = (float*)smem;
  const int tid = threadIdx.x;
  if (tid < 128) lsl[tid] = 1.0f / l[z * 2048 + bx * 128 + tid];
  __syncthreads();

  const int lane = tid & 63;
  const int wave = tid >> 6;
  const int quad = lane >> 4;
  const int l16  = lane & 15;
  const int wm   = (wave & 1) * 64;
  const int wn   = (wave >> 1) * 64;
  float* C = out + (long)z * SU;
#pragma unroll
  for (int mt = 0; mt < 4; mt++)
#pragma unroll
    for (int nt = 0; nt < 4; nt++) {
      const int r0 = bx * 128 + wm + mt * 16 + quad * 4;
      const int lr = wm + mt * 16 + quad * 4;
      const int cc = by * 128 + wn + nt * 16 + l16;
#pragma unroll
      for (int i = 0; i < 4; i++)
        C[(long)(r0 + i) * 768 + cc] = acc[mt][nt][i] * lsl[lr + i];
    }
}

// =====================================================================
extern "C" void kernel_launch(void* const* d_in, const int* in_sizes, int n_in,
                              void* d_out, int out_size, void* d_ws, size_t ws_size,
                              hipStream_t stream) {
  (void)in_sizes; (void)n_in; (void)out_size;
  const float* x  = (const float*)d_in[0];
  const float* Wq = (const float*)d_in[1];
  const float* Wk = (const float*)d_in[2];
  const float* Wv = (const float*)d_in[3];
  float* out = (float*)d_out;

  const long SU = 2048L * 768;

  // Workspace layout (u16 offsets), all disjoint:
  //   Qp   @ 0         (6291456)   Q' = x.Mt packed
  //   Vtp  @ 6291456   (6291456)   V^T packed
  //   xbp  @ 12582912  (6291456)   x packed (B operand of S-GEMM)
  //   wtp  @ 18874368  (589824)    Wv^T packed
  //   wqn  @ 19464192  (589824)    Wq natural packed
  //   wkn  @ 20054016  (589824)    Wk natural packed
  //   mt   @ 20643840  (589824)    Mt = Wk.Wq^T packed
  //   Pp   @ 21233664  (g*4194304)
  //   l    @ after Pp  (8192 floats)
  u16* Qp  = (u16*)d_ws;
  u16* Vtp = Qp + 6291456;
  u16* xbp = Vtp + 6291456;
  u16* wtp = xbp + 6291456;
  u16* wqn = wtp + 589824;
  u16* wkn = wqn + 589824;
  u16* mt  = wkn + 589824;
  u16* Pp  = mt + 589824;

  const size_t base_b = 21233664u * 2u;
  const size_t need4 = base_b + 4u * 8388608u + 32768u;  // 76,054,528
  const size_t need2 = base_b + 2u * 8388608u + 32768u;
  int g = 1;
  if (ws_size >= need4) g = 4;
  else if (ws_size >= need2) g = 2;

  float* l = (float*)((char*)d_ws + base_b + (size_t)g * 8388608u);

  const float qscale = 0.03608439182435161f;  // 1/sqrt(768)

  pack_all<<<dim3(4224), dim3(256), 0, stream>>>(x, Wq, Wk, Wv, xbp, wtp, wqn, wkn);
  gemm_m<<<dim3(44), dim3(256), 0, stream>>>(wkn, wqn, mt, l);
  gemm_proj<<<dim3(384), dim3(512), 0, stream>>>(xbp, wtp, mt, Qp, Vtp);

  for (int b0 = 0; b0 < 4; b0 += g) {
    int gb = 4 - b0 < g ? 4 - b0 : g;
    gemm_s_exp256<<<dim3(8, 8, gb), dim3(512), 0, stream>>>(
        Qp + (long)b0 * 16 * 98304, xbp + (long)b0 * 16 * 98304, Pp,
        l + (long)b0 * 2048, qscale);
    gemm_pv<<<dim3(16, 6, gb), dim3(256), 0, stream>>>(
        Pp, Vtp + (long)b0 * 32 * GR, l + (long)b0 * 2048, out + (long)b0 * SU);
  }
}

// Round 8
// 198.252 us; speedup vs baseline: 1.0269x; 1.0269x over previous
//
#include <hip/hip_runtime.h>
#include <stdint.h>

// Self-attention: x[4,2048,768] fp32, W_q/W_k/W_v [768,768] fp32 -> out[4,2048,768] fp32.
//
// v13: revert to v9 (measured best, 191.9 us) + launch merges only.
//  - v12's M-trick (S = x(WqWk^T)x^T) REGRESSED s_exp 41.5 -> 54 us with no
//    identifiable counter mechanism -> full dataflow revert per discipline.
//  - v9 dataflow restored: K-projection, S = Q.K^T (B = freshly written Kp),
//    s_exp = 256x128 triple-buffered core grid (8,16,g), proj grid 576,
//    PV 128^2 core grid (16,6,g), atomic row-sum l, XCD chunk swizzles.
//  - pack_all: ONE kernel = x-pack (3072 blk) + Wq/Wk/Wv transpose-pack (1728)
//    + l-zeroing (8). Deletes transpose_pack_w launch + hipMemsetAsync.
//    6 launches -> 4.
//
// Packed layout: operand = [row-block r/128][it = k/64][16 KB chunk]; chunk =
// [p = k-octet 0..8][r 0..128][8 u16]. A 32-k piece = half-chunk = 4096 u16.

typedef unsigned short u16;
typedef unsigned int u32;

typedef __attribute__((ext_vector_type(4))) float f32x4;
typedef __attribute__((ext_vector_type(8))) __bf16 bf16x8;
typedef __attribute__((ext_vector_type(8))) short s16x8;
typedef __attribute__((ext_vector_type(8))) unsigned short us16x8;

template <class T> T&& declv();
template <typename T, typename V = void>
struct mfma_ok { static constexpr bool value = false; };
template <typename T>
struct mfma_ok<T, decltype((void)__builtin_amdgcn_mfma_f32_16x16x32_bf16(
                     declv<T>(), declv<T>(), declv<f32x4>(), 0, 0, 0))> {
  static constexpr bool value = true;
};
template <bool BF, bool S16> struct pick_frag { typedef us16x8 type; };
template <bool S16> struct pick_frag<true, S16> { typedef bf16x8 type; };
template <> struct pick_frag<false, true> { typedef s16x8 type; };
typedef typename pick_frag<mfma_ok<bf16x8>::value, mfma_ok<s16x8>::value>::type frag_t;

__device__ inline f32x4 mfma16x16x32(frag_t a, frag_t b, f32x4 c) {
  return __builtin_amdgcn_mfma_f32_16x16x32_bf16(a, b, c, 0, 0, 0);
}

#define AS3(p) ((__attribute__((address_space(3))) void*)(p))
#define AS1c(p) ((__attribute__((address_space(1))) void*)(const void*)(p))

__device__ inline u16 f2bf(float f) {
  union { float f; u32 u; } v; v.f = f;
  u32 r = v.u + 0x7fffu + ((v.u >> 16) & 1u);  // RNE
  return (u16)(r >> 16);
}

#define GR 8192        // u16 per it-chunk (16 KB)
#define BOFF4 8192     // u16 offset of B half of LDS (128^2 loop)

// =====================================================================
// 128x128 / 4-wave loop — gemm_pv only.
// =====================================================================
__device__ inline void gemm_loop4(u16* smem, const u16* __restrict__ Ap,
                                  const u16* __restrict__ Bp, int nit,
                                  f32x4 acc[4][4])
{
  const int tid  = threadIdx.x;
  const int lane = tid & 63;
  const int wave = tid >> 6;
  const int quad = lane >> 4;
  const int l16  = lane & 15;
  const int wm   = (wave & 1) * 64;
  const int wn   = (wave >> 1) * 64;
  const int so   = wave * 2048;
  const int lo   = lane << 3;

#pragma unroll
  for (int i = 0; i < 4; i++)
#pragma unroll
    for (int j = 0; j < 4; j++) acc[i][j] = f32x4{0.f, 0.f, 0.f, 0.f};

  for (int it = 0; it < nit; ++it) {
    const long o = (long)it * GR;
    __syncthreads();
#pragma unroll
    for (int j = 0; j < 4; j++) {
      __builtin_amdgcn_global_load_lds(AS1c(Ap + o + so + j * 512 + lo),
                                       AS3(smem + so + j * 512), 16, 0, 0);
      __builtin_amdgcn_global_load_lds(AS1c(Bp + o + so + j * 512 + lo),
                                       AS3(smem + BOFF4 + so + j * 512), 16, 0, 0);
    }
    __syncthreads();

#pragma unroll
    for (int s = 0; s < 2; s++) {
      frag_t af[4], bf_[4];
#pragma unroll
      for (int mt = 0; mt < 4; mt++)
        af[mt] = *(const frag_t*)(&smem[(s * 4 + quad) * 1024 + (wm + mt * 16 + l16) * 8]);
#pragma unroll
      for (int nt = 0; nt < 4; nt++)
        bf_[nt] = *(const frag_t*)(&smem[BOFF4 + (s * 4 + quad) * 1024 + (wn + nt * 16 + l16) * 8]);
#pragma unroll
      for (int mt = 0; mt < 4; mt++)
#pragma unroll
        for (int nt = 0; nt < 4; nt++)
          acc[mt][nt] = mfma16x16x32(af[mt], bf_[nt], acc[mt][nt]);
    }
  }
}

// =====================================================================
// 256x128 / 8-wave / BK=32 / triple-buffered core (72 KiB LDS) — proj + s_exp.
// =====================================================================
__device__ __forceinline__ void gemm128c_loop(u16* smem,
    const u16* __restrict__ A0, const u16* __restrict__ A1,
    const u16* __restrict__ B0, int nt32, f32x4 acc[4][4])
{
  const int tid   = threadIdx.x;
  const int lane  = tid & 63;
  const int wave  = tid >> 6;      // 0..7
  const int quad  = lane >> 4;
  const int l16   = lane & 15;
  const int waveM = wave >> 1;     // 0..3 (64-row strip)
  const int waveN = wave & 1;      // 0..1 (64-col strip)
  const int wch   = wave * 512;    // wave chunk within a 4096-u16 piece
  const int go    = tid * 8;       // per-lane global offset (u16)

#pragma unroll
  for (int i = 0; i < 4; i++)
#pragma unroll
    for (int j = 0; j < 4; j++) acc[i][j] = f32x4{0.f, 0.f, 0.f, 0.f};

#define STG3(T, BUF) do {                                                      \
    const long _p = (long)(T) * 4096;                                          \
    const int _b = (BUF) * 12288 + wch;                                        \
    __builtin_amdgcn_global_load_lds(AS1c(A0 + _p + go), AS3(smem + _b),       \
                                     16, 0, 0);                                \
    __builtin_amdgcn_global_load_lds(AS1c(A1 + _p + go), AS3(smem + _b + 4096),\
                                     16, 0, 0);                                \
    __builtin_amdgcn_global_load_lds(AS1c(B0 + _p + go), AS3(smem + _b + 8192),\
                                     16, 0, 0);                                \
  } while (0)

  STG3(0, 0);
  STG3(1, 1);
  asm volatile("s_waitcnt vmcnt(3)" ::: "memory");
  __builtin_amdgcn_s_barrier();

  const int ablk = (waveM >> 1) * 4096;
  const int arow = ((waveM & 1) * 64 + l16) * 8;
  const int brow = (waveN * 64 + l16) * 8;

  int bc = 0;  // t % 3
  for (int t = 0; t < nt32; ++t) {
    const int bb = bc * 12288;
    frag_t af[4], bfr[4];
#pragma unroll
    for (int mt = 0; mt < 4; mt++)
      af[mt] = *(const frag_t*)(smem + bb + ablk + quad * 1024 + arow + mt * 128);
#pragma unroll
    for (int nt = 0; nt < 4; nt++)
      bfr[nt] = *(const frag_t*)(smem + bb + 8192 + quad * 1024 + brow + nt * 128);

    if (t + 2 < nt32) {
      const int sc = bc == 0 ? 2 : bc - 1;  // (t+2) % 3
      STG3(t + 2, sc);
    }
    __builtin_amdgcn_s_barrier();
    asm volatile("s_waitcnt lgkmcnt(0)" ::: "memory");
    __builtin_amdgcn_sched_barrier(0);
    __builtin_amdgcn_s_setprio(1);
#pragma unroll
    for (int mt = 0; mt < 4; mt++)
#pragma unroll
      for (int nt = 0; nt < 4; nt++)
        acc[mt][nt] = mfma16x16x32(af[mt], bfr[nt], acc[mt][nt]);
    __builtin_amdgcn_s_setprio(0);

    if (t + 3 <= nt32)      { asm volatile("s_waitcnt vmcnt(3)" ::: "memory"); }
    else if (t + 2 <= nt32) { asm volatile("s_waitcnt vmcnt(0)" ::: "memory"); }
    __builtin_amdgcn_s_barrier();
    bc = bc == 2 ? 0 : bc + 1;
  }
#undef STG3
}

// Packed bf16 epilogue for a 256x128 tile.
__device__ __forceinline__ void epi_pack_rc(u16* smem, u16* __restrict__ dst0,
                                            u16* __restrict__ dst1, f32x4 acc[4][4])
{
  const int tid   = threadIdx.x;
  const int lane  = tid & 63;
  const int wave  = tid >> 6;
  const int quad  = lane >> 4;
  const int l16   = lane & 15;
  const int waveM = wave >> 1;
  const int waveN = wave & 1;

  __syncthreads();
  const int base = (waveM >> 1) * 16384 + waveN * 8192 + (l16 >> 3) * 1024 + (l16 & 7);
  const int rr0  = (waveM & 1) * 64 + quad * 4;
#pragma unroll
  for (int mt = 0; mt < 4; mt++)
#pragma unroll
    for (int nt = 0; nt < 4; nt++) {
#pragma unroll
      for (int i = 0; i < 4; i++)
        smem[base + nt * 2048 + (rr0 + mt * 16 + i) * 8] = f2bf(acc[mt][nt][i]);
    }
  __syncthreads();
#pragma unroll
  for (int k = 0; k < 4; k++) {
    const int idx = k * 4096 + tid * 8;
    *(uint4*)(dst0 + idx) = *(const uint4*)(smem + idx);
    *(uint4*)(dst1 + idx) = *(const uint4*)(smem + 16384 + idx);
  }
}

// Exp + packed + atomic row-sum epilogue for a 256x128 S-tile.
__device__ __forceinline__ void epi_exp_rc(u16* smem, u16* __restrict__ dst0,
                                           u16* __restrict__ dst1,
                                           float* __restrict__ lG,
                                           f32x4 acc[4][4], float qscale)
{
  const int tid   = threadIdx.x;
  const int lane  = tid & 63;
  const int wave  = tid >> 6;
  const int quad  = lane >> 4;
  const int l16   = lane & 15;
  const int waveM = wave >> 1;
  const int waveN = wave & 1;
  float* lrow = (float*)(smem + 32768);  // [256][2] floats (2 KB)

  __syncthreads();
  const int base = (waveM >> 1) * 16384 + waveN * 8192 + (l16 >> 3) * 1024 + (l16 & 7);
  const int rr0  = (waveM & 1) * 64 + quad * 4;
  float s[4][4];
#pragma unroll
  for (int mt = 0; mt < 4; mt++)
#pragma unroll
    for (int i = 0; i < 4; i++) s[mt][i] = 0.f;

#pragma unroll
  for (int mt = 0; mt < 4; mt++)
#pragma unroll
    for (int nt = 0; nt < 4; nt++) {
#pragma unroll
      for (int i = 0; i < 4; i++) {
        float ev = __expf(acc[mt][nt][i] * qscale);
        smem[base + nt * 2048 + (rr0 + mt * 16 + i) * 8] = f2bf(ev);
        s[mt][i] += ev;
      }
    }
#pragma unroll
  for (int mt = 0; mt < 4; mt++)
#pragma unroll
    for (int i = 0; i < 4; i++) {
      float v = s[mt][i];
      v += __shfl_xor(v, 1, 16);
      v += __shfl_xor(v, 2, 16);
      v += __shfl_xor(v, 4, 16);
      v += __shfl_xor(v, 8, 16);
      if (l16 == 0)
        lrow[(waveM * 64 + mt * 16 + quad * 4 + i) * 2 + waveN] = v;
    }
  __syncthreads();
#pragma unroll
  for (int k = 0; k < 4; k++) {
    const int idx = k * 4096 + tid * 8;
    *(uint4*)(dst0 + idx) = *(const uint4*)(smem + idx);
    *(uint4*)(dst1 + idx) = *(const uint4*)(smem + 16384 + idx);
  }
  if (tid < 256) atomicAdd(&lG[tid], lrow[tid * 2] + lrow[tid * 2 + 1]);
}

// =====================================================================
// pack_all: merged input prep (one launch, 4808 blocks x 256 thr).
//  [0,3072)      : x fp32 -> xbp packed (8 elems/thread)
//  [3072,4800)   : Wq/Wk/Wv fp32 -> wtp transposed pack (32x32 tiles);
//                  z = (bid-3072)/576 picks W; wtp blocks z*6..z*6+5
//  [4800,4808)   : zero the atomic row-sum buffer l (32 KB)
// =====================================================================
__global__ __launch_bounds__(256)
void pack_all(const float* __restrict__ x, const float* __restrict__ Wq,
              const float* __restrict__ Wk, const float* __restrict__ Wv,
              u16* __restrict__ xbp, u16* __restrict__ wtp,
              float* __restrict__ l)
{
  __shared__ u16 tile[32][33];
  const int bid = blockIdx.x;
  const int tid = threadIdx.x;

  if (bid < 3072) {  // ---- x pack ----
    const int tg = bid * 256 + tid;
    const int m = tg / 96;
    const int g = tg - m * 96;
    const float4* px = (const float4*)(x + (long)m * 768 + g * 8);
    float4 a = px[0], b = px[1];
    uint4 u;
    u.x = (u32)f2bf(a.x) | ((u32)f2bf(a.y) << 16);
    u.y = (u32)f2bf(a.z) | ((u32)f2bf(a.w) << 16);
    u.z = (u32)f2bf(b.x) | ((u32)f2bf(b.y) << 16);
    u.w = (u32)f2bf(b.z) | ((u32)f2bf(b.w) << 16);
    const long addr = (long)(m >> 7) * 98304 + (g >> 3) * GR + (g & 7) * 1024 + (m & 127) * 8;
    *(uint4*)(xbp + addr) = u;
  } else if (bid < 4800) {  // ---- W transpose pack ----
    const int b1 = bid - 3072;
    const int z = b1 / 576;
    const int rem = b1 - z * 576;
    const float* W = z == 0 ? Wq : (z == 1 ? Wk : Wv);
    const int bx = (rem % 24) * 32;  // u base
    const int by = (rem / 24) * 32;  // d base
    const int tx = tid & 31, ty = tid >> 5;
#pragma unroll
    for (int i = 0; i < 32; i += 8)
      tile[ty + i][tx] = f2bf(W[(long)(by + ty + i) * 768 + bx + tx]);
    __syncthreads();
    if (tid < 128) {
      const int ul = tid >> 2, dg = tid & 3;
      const int u = bx + ul, d0 = by + dg * 8;
      uint4 o;
      u32 w_[4];
#pragma unroll
      for (int i = 0; i < 4; i++)
        w_[i] = (u32)tile[dg * 8 + 2 * i][ul] | ((u32)tile[dg * 8 + 2 * i + 1][ul] << 16);
      o.x = w_[0]; o.y = w_[1]; o.z = w_[2]; o.w = w_[3];
      const long addr = (long)(z * 6 + (u >> 7)) * 98304
                      + (d0 >> 6) * GR + ((d0 >> 3) & 7) * 1024 + (u & 127) * 8;
      *(uint4*)(wtp + addr) = o;
    }
  } else {  // ---- zero l ----
    const int idx = (bid - 4800) * 1024 + tid * 4;
    *(float4*)(l + idx) = float4{0.f, 0.f, 0.f, 0.f};
  }
}

// =====================================================================
// Merged Q/K/V^T projection, 256x128 tiles: grid 576 (v9 exact).
//  x < 384 : QK-proj, bx = x&31 (256-row tile), by = x>>5 (0..5 Q, 6..11 K)
//  x >= 384: V^T-proj, i = x-384, bxv = i>>6 (256-u tile 0..2), byv = i&63
// =====================================================================
__global__ __launch_bounds__(512, 2)
void gemm_proj(const u16* __restrict__ xbp, const u16* __restrict__ wtp,
               u16* __restrict__ Qp, u16* __restrict__ Kp, u16* __restrict__ Vtp)
{
  __shared__ alignas(16) u16 smem[36864];
  f32x4 acc[4][4];
  const int x = blockIdx.x;
  const u16 *A0, *A1, *B0;
  u16 *d0, *d1;
  if (x < 384) {
    const int bx = x & 31, by = x >> 5;
    A0 = xbp + (long)(2 * bx) * 98304;  A1 = A0 + 98304;
    B0 = wtp + (long)by * 98304;
    d0 = (by < 6) ? Qp + (long)(2 * bx) * 98304 + (long)(2 * by) * GR
                  : Kp + (long)(2 * bx) * 98304 + (long)(2 * (by - 6)) * GR;
    d1 = d0 + 98304;
  } else {
    const int i = x - 384;
    const int bxv = i >> 6, byv = i & 63;
    A0 = wtp + (long)(12 + 2 * bxv) * 98304;  A1 = A0 + 98304;
    B0 = xbp + (long)byv * 98304;
    d0 = Vtp + (long)(2 * bxv) * 1048576 + (long)(2 * byv) * GR;
    d1 = d0 + 1048576;
  }
  gemm128c_loop(smem, A0, A1, B0, 24, acc);
  epi_pack_rc(smem, d0, d1, acc);
}

// =====================================================================
// S-GEMM + fused exp/atomic-row-sum, 256x128 tiles: grid (8,16,gb) (v9 exact).
// =====================================================================
__global__ __launch_bounds__(512, 2)
void gemm_s_exp(const u16* __restrict__ Qp, const u16* __restrict__ Kp,
                u16* __restrict__ Pp, float* __restrict__ l, float qscale)
{
  __shared__ alignas(16) u16 smem[36864];
  f32x4 acc[4][4];
  const int nb  = (int)gridDim.z << 7;           // 128 * gb  (divisible by 8)
  const int u   = (int)blockIdx.x + ((int)blockIdx.y << 3) + ((int)blockIdx.z << 7);
  const int cpx = nb >> 3;
  const int wg  = (u & 7) * cpx + (u >> 3);      // bijective chunked swizzle
  const int bx = wg & 7, by = (wg >> 3) & 15, z = wg >> 7;

  const u16* A0 = Qp + (long)(z * 16 + 2 * bx) * 98304;
  const u16* B0 = Kp + (long)(z * 16 + by) * 98304;
  gemm128c_loop(smem, A0, A0 + 98304, B0, 24, acc);
  u16* d0 = Pp + (long)z * 4194304 + (long)(2 * bx) * 262144 + (long)(2 * by) * GR;
  epi_exp_rc(smem, d0, d0 + 262144, l + z * 2048 + bx * 256, acc, qscale);
}

// =====================================================================
// One-shot PV (K=2048, NIT=32), grid (16,6,gb); reads 1/l directly (v9 exact).
// =====================================================================
__global__ __launch_bounds__(256)
void gemm_pv(const u16* __restrict__ Pp, const u16* __restrict__ Vtp_off,
             const float* __restrict__ l, float* __restrict__ out)
{
  __shared__ alignas(16) u16 smem[16384];
  f32x4 acc[4][4];
  const long SU = 2048L * 768;
  const int nb  = 96 * (int)gridDim.z;           // 96*gb (divisible by 8)
  const int u   = (int)blockIdx.x + ((int)blockIdx.y << 4) + (int)blockIdx.z * 96;
  const int cpx = nb >> 3;
  const int wg  = (u & 7) * cpx + (u >> 3);
  const int bx = wg & 15, by = (wg >> 4) % 6, z = wg / 96;

  gemm_loop4(smem,
             Pp + (long)z * 4194304 + (long)bx * 262144,
             Vtp_off + (long)by * 1048576 + (long)(z * 32) * GR,
             32, acc);

  __syncthreads();
  float* lsl = (float*)smem;
  const int tid = threadIdx.x;
  if (tid < 128) lsl[tid] = 1.0f / l[z * 2048 + bx * 128 + tid];
  __syncthreads();

  const int lane = tid & 63;
  const int wave = tid >> 6;
  const int quad = lane >> 4;
  const int l16  = lane & 15;
  const int wm   = (wave & 1) * 64;
  const int wn   = (wave >> 1) * 64;
  float* C = out + (long)z * SU;
#pragma unroll
  for (int mt = 0; mt < 4; mt++)
#pragma unroll
    for (int nt = 0; nt < 4; nt++) {
      const int r0 = bx * 128 + wm + mt * 16 + quad * 4;
      const int lr = wm + mt * 16 + quad * 4;
      const int cc = by * 128 + wn + nt * 16 + l16;
#pragma unroll
      for (int i = 0; i < 4; i++)
        C[(long)(r0 + i) * 768 + cc] = acc[mt][nt][i] * lsl[lr + i];
    }
}

// =====================================================================
extern "C" void kernel_launch(void* const* d_in, const int* in_sizes, int n_in,
                              void* d_out, int out_size, void* d_ws, size_t ws_size,
                              hipStream_t stream) {
  (void)in_sizes; (void)n_in; (void)out_size;
  const float* x  = (const float*)d_in[0];
  const float* Wq = (const float*)d_in[1];
  const float* Wk = (const float*)d_in[2];
  const float* Wv = (const float*)d_in[3];
  float* out = (float*)d_out;

  const long SU = 2048L * 768;

  // Layout (byte offsets from ws base) — v9 exact:
  //   [Qp 12.58M][Kp 12.58M][Vtp 12.58M]                end 37,748,736
  //   [Pp g*8.39M]                                      (overlaps xbp+wtp region)
  //   [l  32 KB]                                        after Pp
  //   xbp @ 37,748,736 (12.58M), wtp @ 50,331,648 (3.54M) — dead after proj.
  u16* Qp  = (u16*)d_ws;
  u16* Kp  = Qp + 6291456;
  u16* Vtp = Kp + 6291456;
  u16* xbp = (u16*)((char*)d_ws + 37748736);
  u16* wtp = (u16*)((char*)d_ws + 50331648);
  u16* Pp  = xbp;  // P overlaps xbp+wtp (dead after proj)

  const size_t need4 = 37748736u + 4u * 8388608u + 32768u;  // 71,335,936
  const size_t need2 = 37748736u + 2u * 8388608u + 32768u;  // 54,558,720
  int g = 1;
  if (ws_size >= need4) g = 4;
  else if (ws_size >= need2) g = 2;

  float* l = (float*)((char*)d_ws + 37748736 + (size_t)g * 8388608);

  const float qscale = 0.03608439182435161f;  // 1/sqrt(768)

  pack_all<<<dim3(4808), dim3(256), 0, stream>>>(x, Wq, Wk, Wv, xbp, wtp, l);
  gemm_proj<<<dim3(576), dim3(512), 0, stream>>>(xbp, wtp, Qp, Kp, Vtp);

  for (int b0 = 0; b0 < 4; b0 += g) {
    int gb = 4 - b0 < g ? 4 - b0 : g;
    gemm_s_exp<<<dim3(8, 16, gb), dim3(512), 0, stream>>>(
        Qp + (long)b0 * 16 * 98304, Kp + (long)b0 * 16 * 98304, Pp,
        l + (long)b0 * 2048, qscale);
    gemm_pv<<<dim3(16, 6, gb), dim3(256), 0, stream>>>(
        Pp, Vtp + (long)b0 * 32 * GR, l + (long)b0 * 2048, out + (long)b0 * SU);
  }
}

// Round 9
// 195.349 us; speedup vs baseline: 1.0422x; 1.0149x over previous
//
#include <hip/hip_runtime.h>
#include <stdint.h>

// Self-attention: x[4,2048,768] fp32, W_q/W_k/W_v [768,768] fp32 -> out[4,2048,768] fp32.
//
// v14: v13 (v9 dataflow + merged pack_all, measured 198.3) with ONE change:
//  - s_exp -> 256x256 8-wave quad-buffered counted-vmcnt core (v11 exact),
//    grid (8,8,g) = 256 blocks = 1 block/CU at g=4, ONE dispatch, atomic
//    row-sum epilogue + bijective XCD chunk swizzle. This core measured
//    ~950 TF active in round 1 (256-block round = 27.1 us) vs the ~600 TF
//    2-phase ceiling every other schedule variant pinned at.
//  - proj (256x128 triple-buffered, grid 576), PV (128^2, grid (16,6,g)),
//    pack_all, workspace layout: byte-for-byte v13.
//
// Packed layout: operand = [row-block r/128][it = k/64][16 KB chunk]; chunk =
// [p = k-octet 0..8][r 0..128][8 u16]. A 32-k piece = half-chunk = 4096 u16.

typedef unsigned short u16;
typedef unsigned int u32;

typedef __attribute__((ext_vector_type(4))) float f32x4;
typedef __attribute__((ext_vector_type(8))) __bf16 bf16x8;
typedef __attribute__((ext_vector_type(8))) short s16x8;
typedef __attribute__((ext_vector_type(8))) unsigned short us16x8;

template <class T> T&& declv();
template <typename T, typename V = void>
struct mfma_ok { static constexpr bool value = false; };
template <typename T>
struct mfma_ok<T, decltype((void)__builtin_amdgcn_mfma_f32_16x16x32_bf16(
                     declv<T>(), declv<T>(), declv<f32x4>(), 0, 0, 0))> {
  static constexpr bool value = true;
};
template <bool BF, bool S16> struct pick_frag { typedef us16x8 type; };
template <bool S16> struct pick_frag<true, S16> { typedef bf16x8 type; };
template <> struct pick_frag<false, true> { typedef s16x8 type; };
typedef typename pick_frag<mfma_ok<bf16x8>::value, mfma_ok<s16x8>::value>::type frag_t;

__device__ inline f32x4 mfma16x16x32(frag_t a, frag_t b, f32x4 c) {
  return __builtin_amdgcn_mfma_f32_16x16x32_bf16(a, b, c, 0, 0, 0);
}

#define AS3(p) ((__attribute__((address_space(3))) void*)(p))
#define AS1c(p) ((__attribute__((address_space(1))) void*)(const void*)(p))

__device__ inline u16 f2bf(float f) {
  union { float f; u32 u; } v; v.f = f;
  u32 r = v.u + 0x7fffu + ((v.u >> 16) & 1u);  // RNE
  return (u16)(r >> 16);
}

#define GR 8192        // u16 per it-chunk (16 KB)
#define BOFF4 8192     // u16 offset of B half of LDS (128^2 loop)

// =====================================================================
// 128x128 / 4-wave loop — gemm_pv only.
// =====================================================================
__device__ inline void gemm_loop4(u16* smem, const u16* __restrict__ Ap,
                                  const u16* __restrict__ Bp, int nit,
                                  f32x4 acc[4][4])
{
  const int tid  = threadIdx.x;
  const int lane = tid & 63;
  const int wave = tid >> 6;
  const int quad = lane >> 4;
  const int l16  = lane & 15;
  const int wm   = (wave & 1) * 64;
  const int wn   = (wave >> 1) * 64;
  const int so   = wave * 2048;
  const int lo   = lane << 3;

#pragma unroll
  for (int i = 0; i < 4; i++)
#pragma unroll
    for (int j = 0; j < 4; j++) acc[i][j] = f32x4{0.f, 0.f, 0.f, 0.f};

  for (int it = 0; it < nit; ++it) {
    const long o = (long)it * GR;
    __syncthreads();
#pragma unroll
    for (int j = 0; j < 4; j++) {
      __builtin_amdgcn_global_load_lds(AS1c(Ap + o + so + j * 512 + lo),
                                       AS3(smem + so + j * 512), 16, 0, 0);
      __builtin_amdgcn_global_load_lds(AS1c(Bp + o + so + j * 512 + lo),
                                       AS3(smem + BOFF4 + so + j * 512), 16, 0, 0);
    }
    __syncthreads();

#pragma unroll
    for (int s = 0; s < 2; s++) {
      frag_t af[4], bf_[4];
#pragma unroll
      for (int mt = 0; mt < 4; mt++)
        af[mt] = *(const frag_t*)(&smem[(s * 4 + quad) * 1024 + (wm + mt * 16 + l16) * 8]);
#pragma unroll
      for (int nt = 0; nt < 4; nt++)
        bf_[nt] = *(const frag_t*)(&smem[BOFF4 + (s * 4 + quad) * 1024 + (wn + nt * 16 + l16) * 8]);
#pragma unroll
      for (int mt = 0; mt < 4; mt++)
#pragma unroll
        for (int nt = 0; nt < 4; nt++)
          acc[mt][nt] = mfma16x16x32(af[mt], bf_[nt], acc[mt][nt]);
    }
  }
}

// =====================================================================
// 256x128 / 8-wave / BK=32 / triple-buffered core (72 KiB LDS) — proj.
// =====================================================================
__device__ __forceinline__ void gemm128c_loop(u16* smem,
    const u16* __restrict__ A0, const u16* __restrict__ A1,
    const u16* __restrict__ B0, int nt32, f32x4 acc[4][4])
{
  const int tid   = threadIdx.x;
  const int lane  = tid & 63;
  const int wave  = tid >> 6;      // 0..7
  const int quad  = lane >> 4;
  const int l16   = lane & 15;
  const int waveM = wave >> 1;     // 0..3 (64-row strip)
  const int waveN = wave & 1;      // 0..1 (64-col strip)
  const int wch   = wave * 512;    // wave chunk within a 4096-u16 piece
  const int go    = tid * 8;       // per-lane global offset (u16)

#pragma unroll
  for (int i = 0; i < 4; i++)
#pragma unroll
    for (int j = 0; j < 4; j++) acc[i][j] = f32x4{0.f, 0.f, 0.f, 0.f};

#define STG3(T, BUF) do {                                                      \
    const long _p = (long)(T) * 4096;                                          \
    const int _b = (BUF) * 12288 + wch;                                        \
    __builtin_amdgcn_global_load_lds(AS1c(A0 + _p + go), AS3(smem + _b),       \
                                     16, 0, 0);                                \
    __builtin_amdgcn_global_load_lds(AS1c(A1 + _p + go), AS3(smem + _b + 4096),\
                                     16, 0, 0);                                \
    __builtin_amdgcn_global_load_lds(AS1c(B0 + _p + go), AS3(smem + _b + 8192),\
                                     16, 0, 0);                                \
  } while (0)

  STG3(0, 0);
  STG3(1, 1);
  asm volatile("s_waitcnt vmcnt(3)" ::: "memory");
  __builtin_amdgcn_s_barrier();

  const int ablk = (waveM >> 1) * 4096;
  const int arow = ((waveM & 1) * 64 + l16) * 8;
  const int brow = (waveN * 64 + l16) * 8;

  int bc = 0;  // t % 3
  for (int t = 0; t < nt32; ++t) {
    const int bb = bc * 12288;
    frag_t af[4], bfr[4];
#pragma unroll
    for (int mt = 0; mt < 4; mt++)
      af[mt] = *(const frag_t*)(smem + bb + ablk + quad * 1024 + arow + mt * 128);
#pragma unroll
    for (int nt = 0; nt < 4; nt++)
      bfr[nt] = *(const frag_t*)(smem + bb + 8192 + quad * 1024 + brow + nt * 128);

    if (t + 2 < nt32) {
      const int sc = bc == 0 ? 2 : bc - 1;  // (t+2) % 3
      STG3(t + 2, sc);
    }
    __builtin_amdgcn_s_barrier();
    asm volatile("s_waitcnt lgkmcnt(0)" ::: "memory");
    __builtin_amdgcn_sched_barrier(0);
    __builtin_amdgcn_s_setprio(1);
#pragma unroll
    for (int mt = 0; mt < 4; mt++)
#pragma unroll
      for (int nt = 0; nt < 4; nt++)
        acc[mt][nt] = mfma16x16x32(af[mt], bfr[nt], acc[mt][nt]);
    __builtin_amdgcn_s_setprio(0);

    if (t + 3 <= nt32)      { asm volatile("s_waitcnt vmcnt(3)" ::: "memory"); }
    else if (t + 2 <= nt32) { asm volatile("s_waitcnt vmcnt(0)" ::: "memory"); }
    __builtin_amdgcn_s_barrier();
    bc = bc == 2 ? 0 : bc + 1;
  }
#undef STG3
}

// =====================================================================
// 256x256 / 8-wave / BK=32 / quad-buffered counted-vmcnt core (128 KiB LDS)
// — s_exp. Measured ~950 TF active (round 1). 2.67 MFMA per ds_read_b128.
// =====================================================================
__device__ __forceinline__ void gemm256_loop(u16* smem,
    const u16* __restrict__ A0, const u16* __restrict__ A1,
    const u16* __restrict__ B0, const u16* __restrict__ B1,
    int nt32, f32x4 acc[8][4])
{
  const int tid   = threadIdx.x;
  const int lane  = tid & 63;
  const int wave  = tid >> 6;      // 0..7
  const int quad  = lane >> 4;
  const int l16   = lane & 15;
  const int waveM = wave >> 2;     // 0..1
  const int waveN = wave & 3;      // 0..3
  const int wch   = wave * 512;
  const int lo    = lane * 8;

#pragma unroll
  for (int i = 0; i < 8; i++)
#pragma unroll
    for (int j = 0; j < 4; j++) acc[i][j] = f32x4{0.f, 0.f, 0.f, 0.f};

#define STAGE2(PA, PB, T, PBASE) do {                                          \
    const long _o = ((long)((T) >> 1) << 13) + (long)(((T) & 1) << 12);        \
    const int _db = (((T) & 3) << 14) + ((PBASE) << 12) + wch;                 \
    __builtin_amdgcn_global_load_lds(AS1c((PA) + _o + wch + lo),               \
                                     AS3(smem + _db), 16, 0, 0);               \
    __builtin_amdgcn_global_load_lds(AS1c((PB) + _o + wch + lo),               \
                                     AS3(smem + _db + 4096), 16, 0, 0);        \
  } while (0)

  STAGE2(A0, A1, 0, 0); STAGE2(B0, B1, 0, 2);
  STAGE2(A0, A1, 1, 0); STAGE2(B0, B1, 1, 2);
  STAGE2(A0, A1, 2, 0); STAGE2(B0, B1, 2, 2);
  asm volatile("s_waitcnt vmcnt(8)" ::: "memory");
  __builtin_amdgcn_s_barrier();

  for (int t = 0; t < nt32; ++t) {
    const int bb = (t & 3) << 14;
    const int aB = bb + (waveM << 12) + quad * 1024 + l16 * 8;
    const int bB = bb + 8192 + ((waveN >> 1) << 12) + quad * 1024
                 + ((waveN & 1) * 64 + l16) * 8;
    frag_t af[4], bfr[4];

    // ---- phase 0 (row-half 0) ----
#pragma unroll
    for (int nt = 0; nt < 4; nt++) bfr[nt] = *(const frag_t*)(smem + bB + nt * 128);
#pragma unroll
    for (int mt = 0; mt < 4; mt++) af[mt] = *(const frag_t*)(smem + aB + mt * 128);
    if (t + 3 < nt32) STAGE2(A0, A1, t + 3, 0);
    __builtin_amdgcn_s_barrier();
    asm volatile("s_waitcnt lgkmcnt(0)" ::: "memory");
    __builtin_amdgcn_sched_barrier(0);
    __builtin_amdgcn_s_setprio(1);
#pragma unroll
    for (int mt = 0; mt < 4; mt++)
#pragma unroll
      for (int nt = 0; nt < 4; nt++)
        acc[mt][nt] = mfma16x16x32(af[mt], bfr[nt], acc[mt][nt]);
    __builtin_amdgcn_s_setprio(0);
    __builtin_amdgcn_s_barrier();

    // ---- phase 1 (row-half 1) ----
#pragma unroll
    for (int mt = 0; mt < 4; mt++) af[mt] = *(const frag_t*)(smem + aB + 512 + mt * 128);
    if (t + 3 < nt32) STAGE2(B0, B1, t + 3, 2);
    __builtin_amdgcn_s_barrier();
    asm volatile("s_waitcnt lgkmcnt(0)" ::: "memory");
    __builtin_amdgcn_sched_barrier(0);
    __builtin_amdgcn_s_setprio(1);
#pragma unroll
    for (int mt = 0; mt < 4; mt++)
#pragma unroll
      for (int nt = 0; nt < 4; nt++)
        acc[4 + mt][nt] = mfma16x16x32(af[mt], bfr[nt], acc[4 + mt][nt]);
    __builtin_amdgcn_s_setprio(0);

    if (t + 4 <= nt32)      { asm volatile("s_waitcnt vmcnt(8)" ::: "memory"); }
    else if (t + 3 <= nt32) { asm volatile("s_waitcnt vmcnt(4)" ::: "memory"); }
    else if (t + 2 <= nt32) { asm volatile("s_waitcnt vmcnt(0)" ::: "memory"); }
    __builtin_amdgcn_s_barrier();
  }
#undef STAGE2
}

// Exp + packed + atomic row-sum epilogue for the 256^2 S-tile.
__device__ __forceinline__ void epi_exp256(u16* smem, u16* __restrict__ dst0,
                                           u16* __restrict__ dst1,
                                           float* __restrict__ lG,
                                           f32x4 acc[8][4], float qscale)
{
  const int tid   = threadIdx.x;
  const int lane  = tid & 63;
  const int wave  = tid >> 6;
  const int quad  = lane >> 4;
  const int l16   = lane & 15;
  const int waveM = wave >> 2;
  const int waveN = wave & 3;
  float* lrow = (float*)(smem + 65536);  // [256][4] floats (4 KB)

  __syncthreads();
  float s[8][4];
#pragma unroll
  for (int m8 = 0; m8 < 8; m8++)
#pragma unroll
    for (int i = 0; i < 4; i++) s[m8][i] = 0.f;

#pragma unroll
  for (int m8 = 0; m8 < 8; m8++)
#pragma unroll
    for (int nt = 0; nt < 4; nt++) {
      const int base = waveM * 32768 + waveN * 8192 + (nt * 2 + (l16 >> 3)) * 1024
                     + (l16 & 7);
#pragma unroll
      for (int i = 0; i < 4; i++) {
        const int r = m8 * 16 + quad * 4 + i;
        float ev = __expf(acc[m8][nt][i] * qscale);
        smem[base + r * 8] = f2bf(ev);
        s[m8][i] += ev;
      }
    }
#pragma unroll
  for (int m8 = 0; m8 < 8; m8++)
#pragma unroll
    for (int i = 0; i < 4; i++) {
      float v = s[m8][i];
      v += __shfl_xor(v, 1, 16);
      v += __shfl_xor(v, 2, 16);
      v += __shfl_xor(v, 4, 16);
      v += __shfl_xor(v, 8, 16);
      if (l16 == 0)
        lrow[(waveM * 128 + m8 * 16 + quad * 4 + i) * 4 + waveN] = v;
    }
  __syncthreads();
#pragma unroll
  for (int k = 0; k < 8; k++) {
    const int idx = k * 4096 + tid * 8;
    *(uint4*)(dst0 + idx) = *(const uint4*)(smem + idx);
    *(uint4*)(dst1 + idx) = *(const uint4*)(smem + 32768 + idx);
  }
  if (tid < 256)
    atomicAdd(&lG[tid],
              lrow[tid * 4] + lrow[tid * 4 + 1] + lrow[tid * 4 + 2] + lrow[tid * 4 + 3]);
}

// Packed bf16 epilogue for a 256x128 tile (proj).
__device__ __forceinline__ void epi_pack_rc(u16* smem, u16* __restrict__ dst0,
                                            u16* __restrict__ dst1, f32x4 acc[4][4])
{
  const int tid   = threadIdx.x;
  const int lane  = tid & 63;
  const int wave  = tid >> 6;
  const int quad  = lane >> 4;
  const int l16   = lane & 15;
  const int waveM = wave >> 1;
  const int waveN = wave & 1;

  __syncthreads();
  const int base = (waveM >> 1) * 16384 + waveN * 8192 + (l16 >> 3) * 1024 + (l16 & 7);
  const int rr0  = (waveM & 1) * 64 + quad * 4;
#pragma unroll
  for (int mt = 0; mt < 4; mt++)
#pragma unroll
    for (int nt = 0; nt < 4; nt++) {
#pragma unroll
      for (int i = 0; i < 4; i++)
        smem[base + nt * 2048 + (rr0 + mt * 16 + i) * 8] = f2bf(acc[mt][nt][i]);
    }
  __syncthreads();
#pragma unroll
  for (int k = 0; k < 4; k++) {
    const int idx = k * 4096 + tid * 8;
    *(uint4*)(dst0 + idx) = *(const uint4*)(smem + idx);
    *(uint4*)(dst1 + idx) = *(const uint4*)(smem + 16384 + idx);
  }
}

// =====================================================================
// pack_all: merged input prep (one launch, 4808 blocks x 256 thr).
//  [0,3072)      : x fp32 -> xbp packed (8 elems/thread)
//  [3072,4800)   : Wq/Wk/Wv fp32 -> wtp transposed pack (32x32 tiles)
//  [4800,4808)   : zero the atomic row-sum buffer l (32 KB)
// =====================================================================
__global__ __launch_bounds__(256)
void pack_all(const float* __restrict__ x, const float* __restrict__ Wq,
              const float* __restrict__ Wk, const float* __restrict__ Wv,
              u16* __restrict__ xbp, u16* __restrict__ wtp,
              float* __restrict__ l)
{
  __shared__ u16 tile[32][33];
  const int bid = blockIdx.x;
  const int tid = threadIdx.x;

  if (bid < 3072) {  // ---- x pack ----
    const int tg = bid * 256 + tid;
    const int m = tg / 96;
    const int g = tg - m * 96;
    const float4* px = (const float4*)(x + (long)m * 768 + g * 8);
    float4 a = px[0], b = px[1];
    uint4 u;
    u.x = (u32)f2bf(a.x) | ((u32)f2bf(a.y) << 16);
    u.y = (u32)f2bf(a.z) | ((u32)f2bf(a.w) << 16);
    u.z = (u32)f2bf(b.x) | ((u32)f2bf(b.y) << 16);
    u.w = (u32)f2bf(b.z) | ((u32)f2bf(b.w) << 16);
    const long addr = (long)(m >> 7) * 98304 + (g >> 3) * GR + (g & 7) * 1024 + (m & 127) * 8;
    *(uint4*)(xbp + addr) = u;
  } else if (bid < 4800) {  // ---- W transpose pack ----
    const int b1 = bid - 3072;
    const int z = b1 / 576;
    const int rem = b1 - z * 576;
    const float* W = z == 0 ? Wq : (z == 1 ? Wk : Wv);
    const int bx = (rem % 24) * 32;  // u base
    const int by = (rem / 24) * 32;  // d base
    const int tx = tid & 31, ty = tid >> 5;
#pragma unroll
    for (int i = 0; i < 32; i += 8)
      tile[ty + i][tx] = f2bf(W[(long)(by + ty + i) * 768 + bx + tx]);
    __syncthreads();
    if (tid < 128) {
      const int ul = tid >> 2, dg = tid & 3;
      const int u = bx + ul, d0 = by + dg * 8;
      uint4 o;
      u32 w_[4];
#pragma unroll
      for (int i = 0; i < 4; i++)
        w_[i] = (u32)tile[dg * 8 + 2 * i][ul] | ((u32)tile[dg * 8 + 2 * i + 1][ul] << 16);
      o.x = w_[0]; o.y = w_[1]; o.z = w_[2]; o.w = w_[3];
      const long addr = (long)(z * 6 + (u >> 7)) * 98304
                      + (d0 >> 6) * GR + ((d0 >> 3) & 7) * 1024 + (u & 127) * 8;
      *(uint4*)(wtp + addr) = o;
    }
  } else {  // ---- zero l ----
    const int idx = (bid - 4800) * 1024 + tid * 4;
    *(float4*)(l + idx) = float4{0.f, 0.f, 0.f, 0.f};
  }
}

// =====================================================================
// Merged Q/K/V^T projection, 256x128 tiles: grid 576 (v9 exact).
// =====================================================================
__global__ __launch_bounds__(512, 2)
void gemm_proj(const u16* __restrict__ xbp, const u16* __restrict__ wtp,
               u16* __restrict__ Qp, u16* __restrict__ Kp, u16* __restrict__ Vtp)
{
  __shared__ alignas(16) u16 smem[36864];
  f32x4 acc[4][4];
  const int x = blockIdx.x;
  const u16 *A0, *A1, *B0;
  u16 *d0, *d1;
  if (x < 384) {
    const int bx = x & 31, by = x >> 5;
    A0 = xbp + (long)(2 * bx) * 98304;  A1 = A0 + 98304;
    B0 = wtp + (long)by * 98304;
    d0 = (by < 6) ? Qp + (long)(2 * bx) * 98304 + (long)(2 * by) * GR
                  : Kp + (long)(2 * bx) * 98304 + (long)(2 * (by - 6)) * GR;
    d1 = d0 + 98304;
  } else {
    const int i = x - 384;
    const int bxv = i >> 6, byv = i & 63;
    A0 = wtp + (long)(12 + 2 * bxv) * 98304;  A1 = A0 + 98304;
    B0 = xbp + (long)byv * 98304;
    d0 = Vtp + (long)(2 * bxv) * 1048576 + (long)(2 * byv) * GR;
    d1 = d0 + 1048576;
  }
  gemm128c_loop(smem, A0, A1, B0, 24, acc);
  epi_pack_rc(smem, d0, d1, acc);
}

// =====================================================================
// S-GEMM + fused exp/atomic-row-sum, 256^2 tiles: grid (8,8,gb) (v11 exact).
// At g=4: 256 blocks = exactly 1/CU, ONE dispatch.
// =====================================================================
__global__ __launch_bounds__(512, 2)
void gemm_s_exp256(const u16* __restrict__ Qp, const u16* __restrict__ Kp,
                   u16* __restrict__ Pp, float* __restrict__ l, float qscale)
{
  __shared__ alignas(16) u16 smem[67584];  // 128 KB image + 4 KB lrow
  f32x4 acc[8][4];
  const int nb  = (int)gridDim.z << 6;           // 64 * gb (divisible by 8)
  const int u   = (int)blockIdx.x + ((int)blockIdx.y << 3) + ((int)blockIdx.z << 6);
  const int cpx = nb >> 3;
  const int wg  = (u & 7) * cpx + (u >> 3);      // bijective chunked swizzle
  const int bx = wg & 7, by = (wg >> 3) & 7, z = wg >> 6;

  const u16* A0 = Qp + (long)(z * 16 + 2 * bx) * 98304;
  const u16* B0 = Kp + (long)(z * 16 + 2 * by) * 98304;
  gemm256_loop(smem, A0, A0 + 98304, B0, B0 + 98304, 24, acc);
  u16* d0 = Pp + (long)z * 4194304 + (long)(2 * bx) * 262144 + (long)(4 * by) * GR;
  epi_exp256(smem, d0, d0 + 262144, l + z * 2048 + bx * 256, acc, qscale);
}

// =====================================================================
// One-shot PV (K=2048, NIT=32), grid (16,6,gb); reads 1/l directly (v9 exact).
// =====================================================================
__global__ __launch_bounds__(256)
void gemm_pv(const u16* __restrict__ Pp, const u16* __restrict__ Vtp_off,
             const float* __restrict__ l, float* __restrict__ out)
{
  __shared__ alignas(16) u16 smem[16384];
  f32x4 acc[4][4];
  const long SU = 2048L * 768;
  const int nb  = 96 * (int)gridDim.z;           // 96*gb (divisible by 8)
  const int u   = (int)blockIdx.x + ((int)blockIdx.y << 4) + (int)blockIdx.z * 96;
  const int cpx = nb >> 3;
  const int wg  = (u & 7) * cpx + (u >> 3);
  const int bx = wg & 15, by = (wg >> 4) % 6, z = wg / 96;

  gemm_loop4(smem,
             Pp + (long)z * 4194304 + (long)bx * 262144,
             Vtp_off + (long)by * 1048576 + (long)(z * 32) * GR,
             32, acc);

  __syncthreads();
  float* lsl = (float*)smem;
  const int tid = threadIdx.x;
  if (tid < 128) lsl[tid] = 1.0f / l[z * 2048 + bx * 128 + tid];
  __syncthreads();

  const int lane = tid & 63;
  const int wave = tid >> 6;
  const int quad = lane >> 4;
  const int l16  = lane & 15;
  const int wm   = (wave & 1) * 64;
  const int wn   = (wave >> 1) * 64;
  float* C = out + (long)z * SU;
#pragma unroll
  for (int mt = 0; mt < 4; mt++)
#pragma unroll
    for (int nt = 0; nt < 4; nt++) {
      const int r0 = bx * 128 + wm + mt * 16 + quad * 4;
      const int lr = wm + mt * 16 + quad * 4;
      const int cc = by * 128 + wn + nt * 16 + l16;
#pragma unroll
      for (int i = 0; i < 4; i++)
        C[(long)(r0 + i) * 768 + cc] = acc[mt][nt][i] * lsl[lr + i];
    }
}

// =====================================================================
extern "C" void kernel_launch(void* const* d_in, const int* in_sizes, int n_in,
                              void* d_out, int out_size, void* d_ws, size_t ws_size,
                              hipStream_t stream) {
  (void)in_sizes; (void)n_in; (void)out_size;
  const float* x  = (const float*)d_in[0];
  const float* Wq = (const float*)d_in[1];
  const float* Wk = (const float*)d_in[2];
  const float* Wv = (const float*)d_in[3];
  float* out = (float*)d_out;

  const long SU = 2048L * 768;

  // Layout (byte offsets from ws base) — v13 exact:
  //   [Qp 12.58M][Kp 12.58M][Vtp 12.58M]                end 37,748,736
  //   [Pp g*8.39M]                                      (overlaps xbp+wtp region)
  //   [l  32 KB]                                        after Pp
  //   xbp @ 37,748,736 (12.58M), wtp @ 50,331,648 (3.54M) — dead after proj.
  u16* Qp  = (u16*)d_ws;
  u16* Kp  = Qp + 6291456;
  u16* Vtp = Kp + 6291456;
  u16* xbp = (u16*)((char*)d_ws + 37748736);
  u16* wtp = (u16*)((char*)d_ws + 50331648);
  u16* Pp  = xbp;  // P overlaps xbp+wtp (dead after proj)

  const size_t need4 = 37748736u + 4u * 8388608u + 32768u;  // 71,335,936
  const size_t need2 = 37748736u + 2u * 8388608u + 32768u;  // 54,558,720
  int g = 1;
  if (ws_size >= need4) g = 4;
  else if (ws_size >= need2) g = 2;

  float* l = (float*)((char*)d_ws + 37748736 + (size_t)g * 8388608);

  const float qscale = 0.03608439182435161f;  // 1/sqrt(768)

  pack_all<<<dim3(4808), dim3(256), 0, stream>>>(x, Wq, Wk, Wv, xbp, wtp, l);
  gemm_proj<<<dim3(576), dim3(512), 0, stream>>>(xbp, wtp, Qp, Kp, Vtp);

  for (int b0 = 0; b0 < 4; b0 += g) {
    int gb = 4 - b0 < g ? 4 - b0 : g;
    gemm_s_exp256<<<dim3(8, 8, gb), dim3(512), 0, stream>>>(
        Qp + (long)b0 * 16 * 98304, Kp + (long)b0 * 16 * 98304, Pp,
        l + (long)b0 * 2048, qscale);
    gemm_pv<<<dim3(16, 6, gb), dim3(256), 0, stream>>>(
        Pp, Vtp + (long)b0 * 32 * GR, l + (long)b0 * 2048, out + (long)b0 * SU);
  }
}

// Round 10
// 187.991 us; speedup vs baseline: 1.0830x; 1.0391x over previous
//
#include <hip/hip_runtime.h>
#include <stdint.h>

// Self-attention: x[4,2048,768] fp32, W_q/W_k/W_v [768,768] fp32 -> out[4,2048,768] fp32.
//
// v15: v14 (195.3 us) with ONE change: PV's K-loop upgraded from the legacy
// drain-everything 2-barrier loop to the proven counted-vmcnt triple-buffer
// structure (the same schedule that took s_exp 42.8 -> 40 in v9):
//  - 128^2 tile, 4 waves, BK=32 pieces; 3 x 16 KB LDS units (48 KiB, 3 blk/CU
//    capacity -> all 384 blocks co-resident); stage tile t+2 while computing t;
//    boundary vmcnt(4), never 0 mid-loop; setprio around the 16-MFMA cluster.
//  - pack_all / proj (256x128 triple-buffered) / s_exp256 (256^2 quad-buffered,
//    1 blk/CU perfect fill) / workspace: byte-for-byte v14.
//
// Packed layout: operand = [row-block r/128][it = k/64][16 KB chunk]; chunk =
// [p = k-octet 0..8][r 0..128][8 u16]. A 32-k piece = half-chunk = 4096 u16.

typedef unsigned short u16;
typedef unsigned int u32;

typedef __attribute__((ext_vector_type(4))) float f32x4;
typedef __attribute__((ext_vector_type(8))) __bf16 bf16x8;
typedef __attribute__((ext_vector_type(8))) short s16x8;
typedef __attribute__((ext_vector_type(8))) unsigned short us16x8;

template <class T> T&& declv();
template <typename T, typename V = void>
struct mfma_ok { static constexpr bool value = false; };
template <typename T>
struct mfma_ok<T, decltype((void)__builtin_amdgcn_mfma_f32_16x16x32_bf16(
                     declv<T>(), declv<T>(), declv<f32x4>(), 0, 0, 0))> {
  static constexpr bool value = true;
};
template <bool BF, bool S16> struct pick_frag { typedef us16x8 type; };
template <bool S16> struct pick_frag<true, S16> { typedef bf16x8 type; };
template <> struct pick_frag<false, true> { typedef s16x8 type; };
typedef typename pick_frag<mfma_ok<bf16x8>::value, mfma_ok<s16x8>::value>::type frag_t;

__device__ inline f32x4 mfma16x16x32(frag_t a, frag_t b, f32x4 c) {
  return __builtin_amdgcn_mfma_f32_16x16x32_bf16(a, b, c, 0, 0, 0);
}

#define AS3(p) ((__attribute__((address_space(3))) void*)(p))
#define AS1c(p) ((__attribute__((address_space(1))) void*)(const void*)(p))

__device__ inline u16 f2bf(float f) {
  union { float f; u32 u; } v; v.f = f;
  u32 r = v.u + 0x7fffu + ((v.u >> 16) & 1u);  // RNE
  return (u16)(r >> 16);
}

#define GR 8192        // u16 per it-chunk (16 KB)

// =====================================================================
// 128x128 / 4-wave / BK=32 / triple-buffered counted-vmcnt core (48 KiB LDS)
// — gemm_pv. Unit u at u*8192 u16: [A piece 4096][B piece 4096].
// Per tile: {8 ds_read_b128, stage tile t+2 (4 gloads), barrier, lgkmcnt(0),
//   sched_barrier, setprio(1), 16 MFMA, setprio(0), boundary vmcnt(4), barrier}.
// Race-free: stage of t+2 targets buf (t+2)%3 == (t-1)%3, whose reads every
// wave drained via lgkmcnt(0) before the end-of-(t-1) barrier.
// =====================================================================
__device__ __forceinline__ void gemm_pv_loop(u16* smem, const u16* __restrict__ Ap,
                                             const u16* __restrict__ Bp, int nt32,
                                             f32x4 acc[4][4])
{
  const int tid  = threadIdx.x;
  const int lane = tid & 63;
  const int wave = tid >> 6;     // 0..3
  const int quad = lane >> 4;
  const int l16  = lane & 15;
  const int wm   = (wave & 1) * 64;
  const int wn   = (wave >> 1) * 64;
  const int to   = tid * 8;      // staging offset (256 thr x 8 u16 = 2048)

#pragma unroll
  for (int i = 0; i < 4; i++)
#pragma unroll
    for (int j = 0; j < 4; j++) acc[i][j] = f32x4{0.f, 0.f, 0.f, 0.f};

#define STGPV(T, BUF) do {                                                     \
    const long _p = (long)(T) * 4096;                                          \
    const int _b = (BUF) * 8192;                                               \
    __builtin_amdgcn_global_load_lds(AS1c(Ap + _p + to), AS3(smem + _b + to),  \
                                     16, 0, 0);                                \
    __builtin_amdgcn_global_load_lds(AS1c(Ap + _p + 2048 + to),                \
                                     AS3(smem + _b + 2048 + to), 16, 0, 0);    \
    __builtin_amdgcn_global_load_lds(AS1c(Bp + _p + to),                       \
                                     AS3(smem + _b + 4096 + to), 16, 0, 0);    \
    __builtin_amdgcn_global_load_lds(AS1c(Bp + _p + 2048 + to),                \
                                     AS3(smem + _b + 6144 + to), 16, 0, 0);    \
  } while (0)

  // Prologue: stage tiles 0,1 (8 loads/thread); wait tile 0 (4 newest pending).
  STGPV(0, 0);
  STGPV(1, 1);
  asm volatile("s_waitcnt vmcnt(4)" ::: "memory");
  __builtin_amdgcn_s_barrier();

  const int arow = (wm + l16) * 8;
  const int brow = (wn + l16) * 8;

  int bc = 0;  // t % 3
  for (int t = 0; t < nt32; ++t) {
    const int bb = bc * 8192;
    frag_t af[4], bfr[4];
#pragma unroll
    for (int mt = 0; mt < 4; mt++)
      af[mt] = *(const frag_t*)(smem + bb + quad * 1024 + arow + mt * 128);
#pragma unroll
    for (int nt = 0; nt < 4; nt++)
      bfr[nt] = *(const frag_t*)(smem + bb + 4096 + quad * 1024 + brow + nt * 128);

    if (t + 2 < nt32) {
      const int sc = bc == 0 ? 2 : bc - 1;  // (t+2) % 3
      STGPV(t + 2, sc);
    }
    __builtin_amdgcn_s_barrier();
    asm volatile("s_waitcnt lgkmcnt(0)" ::: "memory");
    __builtin_amdgcn_sched_barrier(0);
    __builtin_amdgcn_s_setprio(1);
#pragma unroll
    for (int mt = 0; mt < 4; mt++)
#pragma unroll
      for (int nt = 0; nt < 4; nt++)
        acc[mt][nt] = mfma16x16x32(af[mt], bfr[nt], acc[mt][nt]);
    __builtin_amdgcn_s_setprio(0);

    if (t + 3 <= nt32)      { asm volatile("s_waitcnt vmcnt(4)" ::: "memory"); }
    else if (t + 2 <= nt32) { asm volatile("s_waitcnt vmcnt(0)" ::: "memory"); }
    __builtin_amdgcn_s_barrier();
    bc = bc == 2 ? 0 : bc + 1;
  }
#undef STGPV
}

// =====================================================================
// 256x128 / 8-wave / BK=32 / triple-buffered core (72 KiB LDS) — proj.
// =====================================================================
__device__ __forceinline__ void gemm128c_loop(u16* smem,
    const u16* __restrict__ A0, const u16* __restrict__ A1,
    const u16* __restrict__ B0, int nt32, f32x4 acc[4][4])
{
  const int tid   = threadIdx.x;
  const int lane  = tid & 63;
  const int wave  = tid >> 6;      // 0..7
  const int quad  = lane >> 4;
  const int l16   = lane & 15;
  const int waveM = wave >> 1;     // 0..3 (64-row strip)
  const int waveN = wave & 1;      // 0..1 (64-col strip)
  const int wch   = wave * 512;    // wave chunk within a 4096-u16 piece
  const int go    = tid * 8;       // per-lane global offset (u16)

#pragma unroll
  for (int i = 0; i < 4; i++)
#pragma unroll
    for (int j = 0; j < 4; j++) acc[i][j] = f32x4{0.f, 0.f, 0.f, 0.f};

#define STG3(T, BUF) do {                                                      \
    const long _p = (long)(T) * 4096;                                          \
    const int _b = (BUF) * 12288 + wch;                                        \
    __builtin_amdgcn_global_load_lds(AS1c(A0 + _p + go), AS3(smem + _b),       \
                                     16, 0, 0);                                \
    __builtin_amdgcn_global_load_lds(AS1c(A1 + _p + go), AS3(smem + _b + 4096),\
                                     16, 0, 0);                                \
    __builtin_amdgcn_global_load_lds(AS1c(B0 + _p + go), AS3(smem + _b + 8192),\
                                     16, 0, 0);                                \
  } while (0)

  STG3(0, 0);
  STG3(1, 1);
  asm volatile("s_waitcnt vmcnt(3)" ::: "memory");
  __builtin_amdgcn_s_barrier();

  const int ablk = (waveM >> 1) * 4096;
  const int arow = ((waveM & 1) * 64 + l16) * 8;
  const int brow = (waveN * 64 + l16) * 8;

  int bc = 0;  // t % 3
  for (int t = 0; t < nt32; ++t) {
    const int bb = bc * 12288;
    frag_t af[4], bfr[4];
#pragma unroll
    for (int mt = 0; mt < 4; mt++)
      af[mt] = *(const frag_t*)(smem + bb + ablk + quad * 1024 + arow + mt * 128);
#pragma unroll
    for (int nt = 0; nt < 4; nt++)
      bfr[nt] = *(const frag_t*)(smem + bb + 8192 + quad * 1024 + brow + nt * 128);

    if (t + 2 < nt32) {
      const int sc = bc == 0 ? 2 : bc - 1;  // (t+2) % 3
      STG3(t + 2, sc);
    }
    __builtin_amdgcn_s_barrier();
    asm volatile("s_waitcnt lgkmcnt(0)" ::: "memory");
    __builtin_amdgcn_sched_barrier(0);
    __builtin_amdgcn_s_setprio(1);
#pragma unroll
    for (int mt = 0; mt < 4; mt++)
#pragma unroll
      for (int nt = 0; nt < 4; nt++)
        acc[mt][nt] = mfma16x16x32(af[mt], bfr[nt], acc[mt][nt]);
    __builtin_amdgcn_s_setprio(0);

    if (t + 3 <= nt32)      { asm volatile("s_waitcnt vmcnt(3)" ::: "memory"); }
    else if (t + 2 <= nt32) { asm volatile("s_waitcnt vmcnt(0)" ::: "memory"); }
    __builtin_amdgcn_s_barrier();
    bc = bc == 2 ? 0 : bc + 1;
  }
#undef STG3
}

// =====================================================================
// 256x256 / 8-wave / BK=32 / quad-buffered counted-vmcnt core (128 KiB LDS)
// — s_exp. Measured ~950 TF active. 2.67 MFMA per ds_read_b128.
// =====================================================================
__device__ __forceinline__ void gemm256_loop(u16* smem,
    const u16* __restrict__ A0, const u16* __restrict__ A1,
    const u16* __restrict__ B0, const u16* __restrict__ B1,
    int nt32, f32x4 acc[8][4])
{
  const int tid   = threadIdx.x;
  const int lane  = tid & 63;
  const int wave  = tid >> 6;      // 0..7
  const int quad  = lane >> 4;
  const int l16   = lane & 15;
  const int waveM = wave >> 2;     // 0..1
  const int waveN = wave & 3;      // 0..3
  const int wch   = wave * 512;
  const int lo    = lane * 8;

#pragma unroll
  for (int i = 0; i < 8; i++)
#pragma unroll
    for (int j = 0; j < 4; j++) acc[i][j] = f32x4{0.f, 0.f, 0.f, 0.f};

#define STAGE2(PA, PB, T, PBASE) do {                                          \
    const long _o = ((long)((T) >> 1) << 13) + (long)(((T) & 1) << 12);        \
    const int _db = (((T) & 3) << 14) + ((PBASE) << 12) + wch;                 \
    __builtin_amdgcn_global_load_lds(AS1c((PA) + _o + wch + lo),               \
                                     AS3(smem + _db), 16, 0, 0);               \
    __builtin_amdgcn_global_load_lds(AS1c((PB) + _o + wch + lo),               \
                                     AS3(smem + _db + 4096), 16, 0, 0);        \
  } while (0)

  STAGE2(A0, A1, 0, 0); STAGE2(B0, B1, 0, 2);
  STAGE2(A0, A1, 1, 0); STAGE2(B0, B1, 1, 2);
  STAGE2(A0, A1, 2, 0); STAGE2(B0, B1, 2, 2);
  asm volatile("s_waitcnt vmcnt(8)" ::: "memory");
  __builtin_amdgcn_s_barrier();

  for (int t = 0; t < nt32; ++t) {
    const int bb = (t & 3) << 14;
    const int aB = bb + (waveM << 12) + quad * 1024 + l16 * 8;
    const int bB = bb + 8192 + ((waveN >> 1) << 12) + quad * 1024
                 + ((waveN & 1) * 64 + l16) * 8;
    frag_t af[4], bfr[4];

    // ---- phase 0 (row-half 0) ----
#pragma unroll
    for (int nt = 0; nt < 4; nt++) bfr[nt] = *(const frag_t*)(smem + bB + nt * 128);
#pragma unroll
    for (int mt = 0; mt < 4; mt++) af[mt] = *(const frag_t*)(smem + aB + mt * 128);
    if (t + 3 < nt32) STAGE2(A0, A1, t + 3, 0);
    __builtin_amdgcn_s_barrier();
    asm volatile("s_waitcnt lgkmcnt(0)" ::: "memory");
    __builtin_amdgcn_sched_barrier(0);
    __builtin_amdgcn_s_setprio(1);
#pragma unroll
    for (int mt = 0; mt < 4; mt++)
#pragma unroll
      for (int nt = 0; nt < 4; nt++)
        acc[mt][nt] = mfma16x16x32(af[mt], bfr[nt], acc[mt][nt]);
    __builtin_amdgcn_s_setprio(0);
    __builtin_amdgcn_s_barrier();

    // ---- phase 1 (row-half 1) ----
#pragma unroll
    for (int mt = 0; mt < 4; mt++) af[mt] = *(const frag_t*)(smem + aB + 512 + mt * 128);
    if (t + 3 < nt32) STAGE2(B0, B1, t + 3, 2);
    __builtin_amdgcn_s_barrier();
    asm volatile("s_waitcnt lgkmcnt(0)" ::: "memory");
    __builtin_amdgcn_sched_barrier(0);
    __builtin_amdgcn_s_setprio(1);
#pragma unroll
    for (int mt = 0; mt < 4; mt++)
#pragma unroll
      for (int nt = 0; nt < 4; nt++)
        acc[4 + mt][nt] = mfma16x16x32(af[mt], bfr[nt], acc[4 + mt][nt]);
    __builtin_amdgcn_s_setprio(0);

    if (t + 4 <= nt32)      { asm volatile("s_waitcnt vmcnt(8)" ::: "memory"); }
    else if (t + 3 <= nt32) { asm volatile("s_waitcnt vmcnt(4)" ::: "memory"); }
    else if (t + 2 <= nt32) { asm volatile("s_waitcnt vmcnt(0)" ::: "memory"); }
    __builtin_amdgcn_s_barrier();
  }
#undef STAGE2
}

// Exp + packed + atomic row-sum epilogue for the 256^2 S-tile.
__device__ __forceinline__ void epi_exp256(u16* smem, u16* __restrict__ dst0,
                                           u16* __restrict__ dst1,
                                           float* __restrict__ lG,
                                           f32x4 acc[8][4], float qscale)
{
  const int tid   = threadIdx.x;
  const int lane  = tid & 63;
  const int wave  = tid >> 6;
  const int quad  = lane >> 4;
  const int l16   = lane & 15;
  const int waveM = wave >> 2;
  const int waveN = wave & 3;
  float* lrow = (float*)(smem + 65536);  // [256][4] floats (4 KB)

  __syncthreads();
  float s[8][4];
#pragma unroll
  for (int m8 = 0; m8 < 8; m8++)
#pragma unroll
    for (int i = 0; i < 4; i++) s[m8][i] = 0.f;

#pragma unroll
  for (int m8 = 0; m8 < 8; m8++)
#pragma unroll
    for (int nt = 0; nt < 4; nt++) {
      const int base = waveM * 32768 + waveN * 8192 + (nt * 2 + (l16 >> 3)) * 1024
                     + (l16 & 7);
#pragma unroll
      for (int i = 0; i < 4; i++) {
        const int r = m8 * 16 + quad * 4 + i;
        float ev = __expf(acc[m8][nt][i] * qscale);
        smem[base + r * 8] = f2bf(ev);
        s[m8][i] += ev;
      }
    }
#pragma unroll
  for (int m8 = 0; m8 < 8; m8++)
#pragma unroll
    for (int i = 0; i < 4; i++) {
      float v = s[m8][i];
      v += __shfl_xor(v, 1, 16);
      v += __shfl_xor(v, 2, 16);
      v += __shfl_xor(v, 4, 16);
      v += __shfl_xor(v, 8, 16);
      if (l16 == 0)
        lrow[(waveM * 128 + m8 * 16 + quad * 4 + i) * 4 + waveN] = v;
    }
  __syncthreads();
#pragma unroll
  for (int k = 0; k < 8; k++) {
    const int idx = k * 4096 + tid * 8;
    *(uint4*)(dst0 + idx) = *(const uint4*)(smem + idx);
    *(uint4*)(dst1 + idx) = *(const uint4*)(smem + 32768 + idx);
  }
  if (tid < 256)
    atomicAdd(&lG[tid],
              lrow[tid * 4] + lrow[tid * 4 + 1] + lrow[tid * 4 + 2] + lrow[tid * 4 + 3]);
}

// Packed bf16 epilogue for a 256x128 tile (proj).
__device__ __forceinline__ void epi_pack_rc(u16* smem, u16* __restrict__ dst0,
                                            u16* __restrict__ dst1, f32x4 acc[4][4])
{
  const int tid   = threadIdx.x;
  const int lane  = tid & 63;
  const int wave  = tid >> 6;
  const int quad  = lane >> 4;
  const int l16   = lane & 15;
  const int waveM = wave >> 1;
  const int waveN = wave & 1;

  __syncthreads();
  const int base = (waveM >> 1) * 16384 + waveN * 8192 + (l16 >> 3) * 1024 + (l16 & 7);
  const int rr0  = (waveM & 1) * 64 + quad * 4;
#pragma unroll
  for (int mt = 0; mt < 4; mt++)
#pragma unroll
    for (int nt = 0; nt < 4; nt++) {
#pragma unroll
      for (int i = 0; i < 4; i++)
        smem[base + nt * 2048 + (rr0 + mt * 16 + i) * 8] = f2bf(acc[mt][nt][i]);
    }
  __syncthreads();
#pragma unroll
  for (int k = 0; k < 4; k++) {
    const int idx = k * 4096 + tid * 8;
    *(uint4*)(dst0 + idx) = *(const uint4*)(smem + idx);
    *(uint4*)(dst1 + idx) = *(const uint4*)(smem + 16384 + idx);
  }
}

// =====================================================================
// pack_all: merged input prep (one launch, 4808 blocks x 256 thr).
//  [0,3072)      : x fp32 -> xbp packed (8 elems/thread)
//  [3072,4800)   : Wq/Wk/Wv fp32 -> wtp transposed pack (32x32 tiles)
//  [4800,4808)   : zero the atomic row-sum buffer l (32 KB)
// =====================================================================
__global__ __launch_bounds__(256)
void pack_all(const float* __restrict__ x, const float* __restrict__ Wq,
              const float* __restrict__ Wk, const float* __restrict__ Wv,
              u16* __restrict__ xbp, u16* __restrict__ wtp,
              float* __restrict__ l)
{
  __shared__ u16 tile[32][33];
  const int bid = blockIdx.x;
  const int tid = threadIdx.x;

  if (bid < 3072) {  // ---- x pack ----
    const int tg = bid * 256 + tid;
    const int m = tg / 96;
    const int g = tg - m * 96;
    const float4* px = (const float4*)(x + (long)m * 768 + g * 8);
    float4 a = px[0], b = px[1];
    uint4 u;
    u.x = (u32)f2bf(a.x) | ((u32)f2bf(a.y) << 16);
    u.y = (u32)f2bf(a.z) | ((u32)f2bf(a.w) << 16);
    u.z = (u32)f2bf(b.x) | ((u32)f2bf(b.y) << 16);
    u.w = (u32)f2bf(b.z) | ((u32)f2bf(b.w) << 16);
    const long addr = (long)(m >> 7) * 98304 + (g >> 3) * GR + (g & 7) * 1024 + (m & 127) * 8;
    *(uint4*)(xbp + addr) = u;
  } else if (bid < 4800) {  // ---- W transpose pack ----
    const int b1 = bid - 3072;
    const int z = b1 / 576;
    const int rem = b1 - z * 576;
    const float* W = z == 0 ? Wq : (z == 1 ? Wk : Wv);
    const int bx = (rem % 24) * 32;  // u base
    const int by = (rem / 24) * 32;  // d base
    const int tx = tid & 31, ty = tid >> 5;
#pragma unroll
    for (int i = 0; i < 32; i += 8)
      tile[ty + i][tx] = f2bf(W[(long)(by + ty + i) * 768 + bx + tx]);
    __syncthreads();
    if (tid < 128) {
      const int ul = tid >> 2, dg = tid & 3;
      const int u = bx + ul, d0 = by + dg * 8;
      uint4 o;
      u32 w_[4];
#pragma unroll
      for (int i = 0; i < 4; i++)
        w_[i] = (u32)tile[dg * 8 + 2 * i][ul] | ((u32)tile[dg * 8 + 2 * i + 1][ul] << 16);
      o.x = w_[0]; o.y = w_[1]; o.z = w_[2]; o.w = w_[3];
      const long addr = (long)(z * 6 + (u >> 7)) * 98304
                      + (d0 >> 6) * GR + ((d0 >> 3) & 7) * 1024 + (u & 127) * 8;
      *(uint4*)(wtp + addr) = o;
    }
  } else {  // ---- zero l ----
    const int idx = (bid - 4800) * 1024 + tid * 4;
    *(float4*)(l + idx) = float4{0.f, 0.f, 0.f, 0.f};
  }
}

// =====================================================================
// Merged Q/K/V^T projection, 256x128 tiles: grid 576 (v9 exact).
// =====================================================================
__global__ __launch_bounds__(512, 2)
void gemm_proj(const u16* __restrict__ xbp, const u16* __restrict__ wtp,
               u16* __restrict__ Qp, u16* __restrict__ Kp, u16* __restrict__ Vtp)
{
  __shared__ alignas(16) u16 smem[36864];
  f32x4 acc[4][4];
  const int x = blockIdx.x;
  const u16 *A0, *A1, *B0;
  u16 *d0, *d1;
  if (x < 384) {
    const int bx = x & 31, by = x >> 5;
    A0 = xbp + (long)(2 * bx) * 98304;  A1 = A0 + 98304;
    B0 = wtp + (long)by * 98304;
    d0 = (by < 6) ? Qp + (long)(2 * bx) * 98304 + (long)(2 * by) * GR
                  : Kp + (long)(2 * bx) * 98304 + (long)(2 * (by - 6)) * GR;
    d1 = d0 + 98304;
  } else {
    const int i = x - 384;
    const int bxv = i >> 6, byv = i & 63;
    A0 = wtp + (long)(12 + 2 * bxv) * 98304;  A1 = A0 + 98304;
    B0 = xbp + (long)byv * 98304;
    d0 = Vtp + (long)(2 * bxv) * 1048576 + (long)(2 * byv) * GR;
    d1 = d0 + 1048576;
  }
  gemm128c_loop(smem, A0, A1, B0, 24, acc);
  epi_pack_rc(smem, d0, d1, acc);
}

// =====================================================================
// S-GEMM + fused exp/atomic-row-sum, 256^2 tiles: grid (8,8,gb) (v14 exact).
// At g=4: 256 blocks = exactly 1/CU, ONE dispatch.
// =====================================================================
__global__ __launch_bounds__(512, 2)
void gemm_s_exp256(const u16* __restrict__ Qp, const u16* __restrict__ Kp,
                   u16* __restrict__ Pp, float* __restrict__ l, float qscale)
{
  __shared__ alignas(16) u16 smem[67584];  // 128 KB image + 4 KB lrow
  f32x4 acc[8][4];
  const int nb  = (int)gridDim.z << 6;           // 64 * gb (divisible by 8)
  const int u   = (int)blockIdx.x + ((int)blockIdx.y << 3) + ((int)blockIdx.z << 6);
  const int cpx = nb >> 3;
  const int wg  = (u & 7) * cpx + (u >> 3);      // bijective chunked swizzle
  const int bx = wg & 7, by = (wg >> 3) & 7, z = wg >> 6;

  const u16* A0 = Qp + (long)(z * 16 + 2 * bx) * 98304;
  const u16* B0 = Kp + (long)(z * 16 + 2 * by) * 98304;
  gemm256_loop(smem, A0, A0 + 98304, B0, B0 + 98304, 24, acc);
  u16* d0 = Pp + (long)z * 4194304 + (long)(2 * bx) * 262144 + (long)(4 * by) * GR;
  epi_exp256(smem, d0, d0 + 262144, l + z * 2048 + bx * 256, acc, qscale);
}

// =====================================================================
// One-shot PV (K=2048, nt32=64), grid (16,6,gb); counted-vmcnt core;
// reads 1/l directly. XCD chunk swizzle unchanged.
// =====================================================================
__global__ __launch_bounds__(256)
void gemm_pv(const u16* __restrict__ Pp, const u16* __restrict__ Vtp_off,
             const float* __restrict__ l, float* __restrict__ out)
{
  __shared__ alignas(16) u16 smem[24576];  // 48 KiB: 3 x [A 8KB][B 8KB]
  f32x4 acc[4][4];
  const long SU = 2048L * 768;
  const int nb  = 96 * (int)gridDim.z;           // 96*gb (divisible by 8)
  const int u   = (int)blockIdx.x + ((int)blockIdx.y << 4) + (int)blockIdx.z * 96;
  const int cpx = nb >> 3;
  const int wg  = (u & 7) * cpx + (u >> 3);
  const int bx = wg & 15, by = (wg >> 4) % 6, z = wg / 96;

  gemm_pv_loop(smem,
               Pp + (long)z * 4194304 + (long)bx * 262144,
               Vtp_off + (long)by * 1048576 + (long)(z * 32) * GR,
               64, acc);

  __syncthreads();
  float* lsl = (float*)smem;
  const int tid = threadIdx.x;
  if (tid < 128) lsl[tid] = 1.0f / l[z * 2048 + bx * 128 + tid];
  __syncthreads();

  const int lane = tid & 63;
  const int wave = tid >> 6;
  const int quad = lane >> 4;
  const int l16  = lane & 15;
  const int wm   = (wave & 1) * 64;
  const int wn   = (wave >> 1) * 64;
  float* C = out + (long)z * SU;
#pragma unroll
  for (int mt = 0; mt < 4; mt++)
#pragma unroll
    for (int nt = 0; nt < 4; nt++) {
      const int r0 = bx * 128 + wm + mt * 16 + quad * 4;
      const int lr = wm + mt * 16 + quad * 4;
      const int cc = by * 128 + wn + nt * 16 + l16;
#pragma unroll
      for (int i = 0; i < 4; i++)
        C[(long)(r0 + i) * 768 + cc] = acc[mt][nt][i] * lsl[lr + i];
    }
}

// =====================================================================
extern "C" void kernel_launch(void* const* d_in, const int* in_sizes, int n_in,
                              void* d_out, int out_size, void* d_ws, size_t ws_size,
                              hipStream_t stream) {
  (void)in_sizes; (void)n_in; (void)out_size;
  const float* x  = (const float*)d_in[0];
  const float* Wq = (const float*)d_in[1];
  const float* Wk = (const float*)d_in[2];
  const float* Wv = (const float*)d_in[3];
  float* out = (float*)d_out;

  const long SU = 2048L * 768;

  // Layout (byte offsets from ws base) — v13/v14 exact:
  //   [Qp 12.58M][Kp 12.58M][Vtp 12.58M]                end 37,748,736
  //   [Pp g*8.39M]                                      (overlaps xbp+wtp region)
  //   [l  32 KB]                                        after Pp
  //   xbp @ 37,748,736 (12.58M), wtp @ 50,331,648 (3.54M) — dead after proj.
  u16* Qp  = (u16*)d_ws;
  u16* Kp  = Qp + 6291456;
  u16* Vtp = Kp + 6291456;
  u16* xbp = (u16*)((char*)d_ws + 37748736);
  u16* wtp = (u16*)((char*)d_ws + 50331648);
  u16* Pp  = xbp;  // P overlaps xbp+wtp (dead after proj)

  const size_t need4 = 37748736u + 4u * 8388608u + 32768u;  // 71,335,936
  const size_t need2 = 37748736u + 2u * 8388608u + 32768u;  // 54,558,720
  int g = 1;
  if (ws_size >= need4) g = 4;
  else if (ws_size >= need2) g = 2;

  float* l = (float*)((char*)d_ws + 37748736 + (size_t)g * 8388608);

  const float qscale = 0.03608439182435161f;  // 1/sqrt(768)

  pack_all<<<dim3(4808), dim3(256), 0, stream>>>(x, Wq, Wk, Wv, xbp, wtp, l);
  gemm_proj<<<dim3(576), dim3(512), 0, stream>>>(xbp, wtp, Qp, Kp, Vtp);

  for (int b0 = 0; b0 < 4; b0 += g) {
    int gb = 4 - b0 < g ? 4 - b0 : g;
    gemm_s_exp256<<<dim3(8, 8, gb), dim3(512), 0, stream>>>(
        Qp + (long)b0 * 16 * 98304, Kp + (long)b0 * 16 * 98304, Pp,
        l + (long)b0 * 2048, qscale);
    gemm_pv<<<dim3(16, 6, gb), dim3(256), 0, stream>>>(
        Pp, Vtp + (long)b0 * 32 * GR, l + (long)b0 * 2048, out + (long)b0 * SU);
  }
}